// Round 1
// baseline (372.012 us; speedup 1.0000x reference)
//
#include <hip/hip_runtime.h>
#include <cstdint>
#include <cstddef>

#define BB 8
#define NN 2048
#define DD 256
#define EE 16
#define HH 8
#define DHD 32
#define CAPC 256
#define BN (BB*NN)   // 16384

// ---------------------------------------------------------------- gating
__global__ __launch_bounds__(256) void gating_kernel(
    const float* __restrict__ x, const float* __restrict__ wg,
    int* __restrict__ idx1a, int* __restrict__ idx2a,
    float* __restrict__ g1a, float* __restrict__ g2a,
    float* __restrict__ raw_sum, float* __restrict__ cnt1)
{
  __shared__ float wgS[DD*EE];
  int tid = threadIdx.x;
  for (int t = tid; t < DD*EE; t += 256) wgS[t] = wg[t];
  __syncthreads();
  int token = blockIdx.x * 256 + tid;
  const float4* xr = (const float4*)(x + (size_t)token * DD);
  float lg[16];
#pragma unroll
  for (int e = 0; e < 16; ++e) lg[e] = 0.f;
  const float4* wg4 = (const float4*)wgS;
  for (int d4 = 0; d4 < DD/4; ++d4) {
    float4 xv = xr[d4];
    float xa[4] = {xv.x, xv.y, xv.z, xv.w};
#pragma unroll
    for (int dd = 0; dd < 4; ++dd) {
      float xc = xa[dd];
      int d = d4*4 + dd;
#pragma unroll
      for (int j = 0; j < 4; ++j) {
        float4 w = wg4[d*4 + j];
        lg[4*j+0] += xc * w.x;
        lg[4*j+1] += xc * w.y;
        lg[4*j+2] += xc * w.z;
        lg[4*j+3] += xc * w.w;
      }
    }
  }
  float mx = lg[0];
#pragma unroll
  for (int e = 1; e < 16; ++e) mx = fmaxf(mx, lg[e]);
  float p[16]; float s = 0.f;
#pragma unroll
  for (int e = 0; e < 16; ++e) { p[e] = expf(lg[e] - mx); s += p[e]; }
  // top-1, first-index on ties (matches np.argmax)
  int i1 = 0; float b1 = p[0];
#pragma unroll
  for (int e = 1; e < 16; ++e) { if (p[e] > b1) { b1 = p[e]; i1 = e; } }
  // top-2 over raw*(1-m1): entry at i1 is exactly 0
  float b2 = (i1 == 0) ? 0.f : p[0]; int i2 = 0;
#pragma unroll
  for (int e = 1; e < 16; ++e) { float v = (e == i1) ? 0.f : p[e]; if (v > b2) { b2 = v; i2 = e; } }
  float inv = 1.f / s;
  float g1 = b1 * inv, g2 = b2 * inv;
  float den = g1 + g2 + 1e-9f;
  g1 /= den; g2 /= den;
  idx1a[token] = i1; idx2a[token] = i2;
  g1a[token] = g1; g2a[token] = g2;
  // loss partials: sum of raw probs and count of idx1 per (b,e)
  int b = token >> 11;
  int lane = tid & 63;
#pragma unroll
  for (int e = 0; e < 16; ++e) {
    float v = p[e] * inv;
    v += __shfl_down(v, 32); v += __shfl_down(v, 16);
    v += __shfl_down(v, 8);  v += __shfl_down(v, 4);
    v += __shfl_down(v, 2);  v += __shfl_down(v, 1);
    unsigned long long mb = __ballot(i1 == e);
    if (lane == 0) {
      atomicAdd(&raw_sum[b*16 + e], v);
      atomicAdd(&cnt1[b*16 + e], (float)__popcll(mb));
    }
  }
}

// ---------------------------------------------------------------- position scan (per batch)
__global__ __launch_bounds__(256) void scan_kernel(
    const int* __restrict__ idx1a, const int* __restrict__ idx2a,
    const float* __restrict__ g1a, const float* __restrict__ g2a,
    float* __restrict__ g1f, float* __restrict__ g2f, int* __restrict__ slot_token)
{
  __shared__ unsigned long long m1s[16][32], m2s[16][32];
  __shared__ int wp1[16][32], wp2[16][32], mcnt[16];
  int b = blockIdx.x, tid = threadIdx.x;
  int wave = tid >> 6, lane = tid & 63;
  for (int w = wave; w < 32; w += 4) {
    int token = b*NN + w*64 + lane;
    int i1 = idx1a[token], i2 = idx2a[token];
#pragma unroll
    for (int e = 0; e < 16; ++e) {
      unsigned long long ma = __ballot(i1 == e);
      unsigned long long mb = __ballot(i2 == e);
      if (lane == 0) { m1s[e][w] = ma; m2s[e][w] = mb; }
    }
  }
  __syncthreads();
  if (tid < 16) {
    int run = 0;
    for (int w = 0; w < 32; ++w) { wp1[tid][w] = run; run += (int)__popcll(m1s[tid][w]); }
    mcnt[tid] = run < CAPC ? run : CAPC;   // m1_count = sum of truncated m1
  } else if (tid < 32) {
    int e2 = tid - 16; int run = 0;
    for (int w = 0; w < 32; ++w) { wp2[e2][w] = run; run += (int)__popcll(m2s[e2][w]); }
  }
  __syncthreads();
  for (int w = wave; w < 32; w += 4) {
    int token = b*NN + w*64 + lane;
    int i1 = idx1a[token], i2 = idx2a[token];
    unsigned long long lt = (1ull << lane) - 1ull;
    int pos1 = wp1[i1][w] + (int)__popcll(m1s[i1][w] & lt);
    float g1 = g1a[token];
    bool k1 = pos1 < CAPC;
    g1f[token] = k1 ? g1 : 0.f;
    if (k1) slot_token[(i1*BB + b)*CAPC + pos1] = token;   // g1 always > 0 -> dispatch=kept
    int pos2 = mcnt[i2] + wp2[i2][w] + (int)__popcll(m2s[i2][w] & lt);
    float g2 = g2a[token];
    bool k2 = pos2 < CAPC;
    g2f[token] = k2 ? g2 : 0.f;
    if (k2 && g2 > 0.f) slot_token[(i2*BB + b)*CAPC + pos2] = token;  // dispatch = combine>0
  }
}

// ---------------------------------------------------------------- loss
__global__ __launch_bounds__(128) void loss_kernel(
    const float* __restrict__ raw_sum, const float* __restrict__ cnt1,
    float* __restrict__ out_loss)
{
  int t = threadIdx.x;
  float v = (raw_sum[t] * (1.f/(float)NN)) * (cnt1[t] * (1.f/(float)NN));
  v += __shfl_down(v, 32); v += __shfl_down(v, 16); v += __shfl_down(v, 8);
  v += __shfl_down(v, 4);  v += __shfl_down(v, 2);  v += __shfl_down(v, 1);
  __shared__ float r2[2];
  if ((t & 63) == 0) r2[t >> 6] = v;
  __syncthreads();
  if (t == 0)
    out_loss[0] = (r2[0] + r2[1]) * ((float)(EE*EE) / (float)(BB*EE)) * 0.01f;
}

// ---------------------------------------------------------------- q = audio @ Wq  (per e,b)
__global__ __launch_bounds__(256) void q_kernel(
    const float* __restrict__ audio, const float* __restrict__ Wq, float* __restrict__ qv)
{
  __shared__ float aS[DD];
  int tid = threadIdx.x, eb = blockIdx.x, e = eb >> 3, b = eb & 7;
  aS[tid] = audio[b*DD + tid];
  __syncthreads();
  const float* w = Wq + (size_t)e * DD * DD;
  float acc = 0.f;
  for (int k = 0; k < DD; ++k) acc += aS[k] * w[(size_t)k*DD + tid];
  qv[(size_t)eb*DD + tid] = acc;
}

// ---------------------------------------------------------------- attention per (e,b,h)
__global__ __launch_bounds__(256) void attn_kernel(
    const float* __restrict__ x, const float* __restrict__ Wkv,
    const float* __restrict__ qv, const int* __restrict__ slot_token,
    float* __restrict__ ov)
{
  __shared__ union {
    float4 wkv[256][16];                                    // 64 KB, phase 1
    struct { float v[256][33]; float attn[256]; float red[16]; } p2;  // phase 2
  } sm;
  int tid = threadIdx.x;
  int eb = blockIdx.x;          // e*8 + b
  int e  = eb >> 3;
  int h  = blockIdx.y;
  const float* wbase = Wkv + (size_t)e * (DD * 2 * DD);
  // stage Wkv head slice: cols [h*32, h*32+32) for k and [256+h*32, ...) for v
  for (int t = tid; t < 4096; t += 256) {
    int d = t >> 4, j = t & 15;
    int col = (j < 8) ? (h*DHD + j*4) : (2*DD/2 + h*DHD + (j-8)*4);  // 256 + ...
    sm.wkv[d][j] = *(const float4*)(wbase + (size_t)d*(2*DD) + col);
  }
  __syncthreads();
  int c = tid;
  int token = slot_token[eb*CAPC + c];
  float ka[32], va[32];
#pragma unroll
  for (int i = 0; i < 32; ++i) { ka[i] = 0.f; va[i] = 0.f; }
  if (token >= 0) {
    const float4* xr = (const float4*)(x + (size_t)token * DD);
    for (int d4 = 0; d4 < 64; ++d4) {
      float4 xvv = xr[d4];
      float xa[4] = {xvv.x, xvv.y, xvv.z, xvv.w};
#pragma unroll
      for (int dd = 0; dd < 4; ++dd) {
        float xc = xa[dd];
        int d = d4*4 + dd;
#pragma unroll
        for (int j = 0; j < 8; ++j) {
          float4 wk = sm.wkv[d][j];
          ka[4*j+0] += xc*wk.x; ka[4*j+1] += xc*wk.y;
          ka[4*j+2] += xc*wk.z; ka[4*j+3] += xc*wk.w;
          float4 wv = sm.wkv[d][8+j];
          va[4*j+0] += xc*wv.x; va[4*j+1] += xc*wv.y;
          va[4*j+2] += xc*wv.z; va[4*j+3] += xc*wv.w;
        }
      }
    }
  }
  float logit = 0.f;
  if (token >= 0) {
    const float* qr = qv + (size_t)eb*DD + h*DHD;
#pragma unroll
    for (int i = 0; i < 32; ++i) logit += ka[i] * qr[i];
    logit *= 0.17677669529663687f;   // 32^-0.5
  }
  __syncthreads();   // done reading sm.wkv -> safe to overwrite with p2
#pragma unroll
  for (int i = 0; i < 32; ++i) sm.p2.v[c][i] = va[i];
  // block softmax over 256 slots (empty slots logit = 0, as in reference)
  int lane = tid & 63, wave = tid >> 6;
  float m = logit;
  m = fmaxf(m, __shfl_down(m, 32)); m = fmaxf(m, __shfl_down(m, 16));
  m = fmaxf(m, __shfl_down(m, 8));  m = fmaxf(m, __shfl_down(m, 4));
  m = fmaxf(m, __shfl_down(m, 2));  m = fmaxf(m, __shfl_down(m, 1));
  if (lane == 0) sm.p2.red[wave] = m;
  __syncthreads();
  float mx = fmaxf(fmaxf(sm.p2.red[0], sm.p2.red[1]), fmaxf(sm.p2.red[2], sm.p2.red[3]));
  float ex = expf(logit - mx);
  float ss = ex;
  ss += __shfl_down(ss, 32); ss += __shfl_down(ss, 16); ss += __shfl_down(ss, 8);
  ss += __shfl_down(ss, 4);  ss += __shfl_down(ss, 2);  ss += __shfl_down(ss, 1);
  if (lane == 0) sm.p2.red[8 + wave] = ss;
  __syncthreads();
  float denom = sm.p2.red[8] + sm.p2.red[9] + sm.p2.red[10] + sm.p2.red[11];
  sm.p2.attn[c] = ex / denom;
  __syncthreads();
  if (tid < 32) {
    float o = 0.f;
    for (int cc = 0; cc < 256; ++cc) o += sm.p2.attn[cc] * sm.p2.v[cc][tid];
    ov[(size_t)eb*DD + h*DHD + tid] = o;
  }
}

// ---------------------------------------------------------------- gate = sigmoid(o @ Wp + bp)
__global__ __launch_bounds__(256) void gate_kernel(
    const float* __restrict__ ov, const float* __restrict__ Wp,
    const float* __restrict__ bp, float* __restrict__ gateW)
{
  __shared__ float oS[DD];
  int tid = threadIdx.x, eb = blockIdx.x, e = eb >> 3;
  oS[tid] = ov[(size_t)eb*DD + tid];
  __syncthreads();
  const float* wp = Wp + (size_t)e * DD * DD;
  float s = bp[e*DD + tid];
  for (int j = 0; j < DD; ++j) s += oS[j] * wp[(size_t)j*DD + tid];
  gateW[(size_t)eb*DD + tid] = 1.f / (1.f + expf(-s));
}

// ---------------------------------------------------------------- recombine
__global__ __launch_bounds__(256) void out_kernel(
    const float* __restrict__ x, const float* __restrict__ g1f, const float* __restrict__ g2f,
    const int* __restrict__ idx1a, const int* __restrict__ idx2a,
    const float* __restrict__ gateW, float* __restrict__ out)
{
  int t = blockIdx.x, tid = threadIdx.x;
  int b = t >> 11;
  float g1 = g1f[t], g2 = g2f[t];
  int e1 = idx1a[t], e2 = idx2a[t];
  float gv = g1 * gateW[(size_t)(e1*BB + b)*DD + tid]
           + g2 * gateW[(size_t)(e2*BB + b)*DD + tid];
  out[(size_t)t*DD + tid] = x[(size_t)t*DD + tid] * gv;
}

// ---------------------------------------------------------------- launcher
extern "C" void kernel_launch(void* const* d_in, const int* in_sizes, int n_in,
                              void* d_out, int out_size, void* d_ws, size_t ws_size,
                              hipStream_t stream)
{
  const float* x     = (const float*)d_in[0];
  const float* audio = (const float*)d_in[1];
  const float* wg    = (const float*)d_in[2];
  const float* Wq    = (const float*)d_in[3];
  const float* Wkv   = (const float*)d_in[4];
  const float* Wp    = (const float*)d_in[5];
  const float* bp    = (const float*)d_in[6];
  float* out = (float*)d_out;

  // workspace layout (~0.9 MB)
  float* raw_sum = (float*)d_ws;                 // 128
  float* cnt1    = raw_sum + 128;                // 128
  int*   idx1a   = (int*)(cnt1 + 128);           // BN
  int*   idx2a   = idx1a + BN;                   // BN
  float* g1a     = (float*)(idx2a + BN);         // BN
  float* g2a     = g1a + BN;                     // BN
  float* g1f     = g2a + BN;                     // BN
  float* g2f     = g1f + BN;                     // BN
  int*   slot_token = (int*)(g2f + BN);          // E*B*CAP = 32768
  float* qv      = (float*)(slot_token + EE*BB*CAPC);  // E*B*D
  float* ov      = qv + EE*BB*DD;                      // E*B*D
  float* gateW   = ov + EE*BB*DD;                      // E*B*D

  hipMemsetAsync(raw_sum, 0, 256*sizeof(float), stream);
  hipMemsetAsync(slot_token, 0xFF, (size_t)EE*BB*CAPC*sizeof(int), stream);  // -1

  gating_kernel<<<BN/256, 256, 0, stream>>>(x, wg, idx1a, idx2a, g1a, g2a, raw_sum, cnt1);
  scan_kernel<<<BB, 256, 0, stream>>>(idx1a, idx2a, g1a, g2a, g1f, g2f, slot_token);
  loss_kernel<<<1, 128, 0, stream>>>(raw_sum, cnt1, out + (size_t)out_size - 1);
  q_kernel<<<EE*BB, 256, 0, stream>>>(audio, Wq, qv);
  attn_kernel<<<dim3(EE*BB, HH), 256, 0, stream>>>(x, Wkv, qv, slot_token, ov);
  gate_kernel<<<EE*BB, 256, 0, stream>>>(ov, Wp, bp, gateW);
  out_kernel<<<BN, 256, 0, stream>>>(x, g1f, g2f, idx1a, idx2a, gateW, out);
}

// Round 2
// 293.122 us; speedup vs baseline: 1.2691x; 1.2691x over previous
//
#include <hip/hip_runtime.h>
#include <cstdint>
#include <cstddef>

#define BB 8
#define NN 2048
#define DD 256
#define EE 16
#define HH 8
#define CAPC 256
#define BN (BB*NN)   // 16384
#define EB (EE*BB)   // 128

// ---------------------------------------------------------------- gating
__global__ __launch_bounds__(256) void gating_kernel(
    const float* __restrict__ x, const float* __restrict__ wg,
    int* __restrict__ idx1a, int* __restrict__ idx2a,
    float* __restrict__ g1a, float* __restrict__ g2a,
    float* __restrict__ raw_sum, float* __restrict__ cnt1)
{
  __shared__ float wgS[DD*EE];
  int tid = threadIdx.x;
  for (int t = tid; t < DD*EE; t += 256) wgS[t] = wg[t];
  __syncthreads();
  int token = blockIdx.x * 256 + tid;
  const float4* xr = (const float4*)(x + (size_t)token * DD);
  float lg[16];
#pragma unroll
  for (int e = 0; e < 16; ++e) lg[e] = 0.f;
  const float4* wg4 = (const float4*)wgS;
  for (int d4 = 0; d4 < DD/4; ++d4) {
    float4 xv = xr[d4];
    float xa[4] = {xv.x, xv.y, xv.z, xv.w};
#pragma unroll
    for (int dd = 0; dd < 4; ++dd) {
      float xc = xa[dd];
      int d = d4*4 + dd;
#pragma unroll
      for (int j = 0; j < 4; ++j) {
        float4 w = wg4[d*4 + j];
        lg[4*j+0] += xc * w.x;
        lg[4*j+1] += xc * w.y;
        lg[4*j+2] += xc * w.z;
        lg[4*j+3] += xc * w.w;
      }
    }
  }
  float mx = lg[0];
#pragma unroll
  for (int e = 1; e < 16; ++e) mx = fmaxf(mx, lg[e]);
  float p[16]; float s = 0.f;
#pragma unroll
  for (int e = 0; e < 16; ++e) { p[e] = expf(lg[e] - mx); s += p[e]; }
  // top-1, first-index on ties (matches np.argmax)
  int i1 = 0; float b1 = p[0];
#pragma unroll
  for (int e = 1; e < 16; ++e) { if (p[e] > b1) { b1 = p[e]; i1 = e; } }
  float b2 = (i1 == 0) ? 0.f : p[0]; int i2 = 0;
#pragma unroll
  for (int e = 1; e < 16; ++e) { float v = (e == i1) ? 0.f : p[e]; if (v > b2) { b2 = v; i2 = e; } }
  float inv = 1.f / s;
  float g1 = b1 * inv, g2 = b2 * inv;
  float den = g1 + g2 + 1e-9f;
  g1 /= den; g2 /= den;
  idx1a[token] = i1; idx2a[token] = i2;
  g1a[token] = g1; g2a[token] = g2;
  int b = token >> 11;
  int lane = tid & 63;
#pragma unroll
  for (int e = 0; e < 16; ++e) {
    float v = p[e] * inv;
    v += __shfl_down(v, 32); v += __shfl_down(v, 16);
    v += __shfl_down(v, 8);  v += __shfl_down(v, 4);
    v += __shfl_down(v, 2);  v += __shfl_down(v, 1);
    unsigned long long mb = __ballot(i1 == e);
    if (lane == 0) {
      atomicAdd(&raw_sum[b*16 + e], v);
      atomicAdd(&cnt1[b*16 + e], (float)__popcll(mb));
    }
  }
}

// ---------------------------------------------------------------- position scan (per batch)
__global__ __launch_bounds__(256) void scan_kernel(
    const int* __restrict__ idx1a, const int* __restrict__ idx2a,
    const float* __restrict__ g1a, const float* __restrict__ g2a,
    float* __restrict__ g1f, float* __restrict__ g2f, int* __restrict__ slot_token)
{
  __shared__ unsigned long long m1s[16][32], m2s[16][32];
  __shared__ int wp1[16][32], wp2[16][32], mcnt[16];
  int b = blockIdx.x, tid = threadIdx.x;
  int wave = tid >> 6, lane = tid & 63;
  for (int w = wave; w < 32; w += 4) {
    int token = b*NN + w*64 + lane;
    int i1 = idx1a[token], i2 = idx2a[token];
#pragma unroll
    for (int e = 0; e < 16; ++e) {
      unsigned long long ma = __ballot(i1 == e);
      unsigned long long mb = __ballot(i2 == e);
      if (lane == 0) { m1s[e][w] = ma; m2s[e][w] = mb; }
    }
  }
  __syncthreads();
  if (tid < 16) {
    int run = 0;
    for (int w = 0; w < 32; ++w) { wp1[tid][w] = run; run += (int)__popcll(m1s[tid][w]); }
    mcnt[tid] = run < CAPC ? run : CAPC;
  } else if (tid < 32) {
    int e2 = tid - 16; int run = 0;
    for (int w = 0; w < 32; ++w) { wp2[e2][w] = run; run += (int)__popcll(m2s[e2][w]); }
  }
  __syncthreads();
  for (int w = wave; w < 32; w += 4) {
    int token = b*NN + w*64 + lane;
    int i1 = idx1a[token], i2 = idx2a[token];
    unsigned long long lt = (1ull << lane) - 1ull;
    int pos1 = wp1[i1][w] + (int)__popcll(m1s[i1][w] & lt);
    float g1 = g1a[token];
    bool k1 = pos1 < CAPC;
    g1f[token] = k1 ? g1 : 0.f;
    if (k1) slot_token[(i1*BB + b)*CAPC + pos1] = token;
    int pos2 = mcnt[i2] + wp2[i2][w] + (int)__popcll(m2s[i2][w] & lt);
    float g2 = g2a[token];
    bool k2 = pos2 < CAPC;
    g2f[token] = k2 ? g2 : 0.f;
    if (k2 && g2 > 0.f) slot_token[(i2*BB + b)*CAPC + pos2] = token;
  }
}

// ---------------------------------------------------------------- loss
__global__ __launch_bounds__(128) void loss_kernel(
    const float* __restrict__ raw_sum, const float* __restrict__ cnt1,
    float* __restrict__ out_loss)
{
  int t = threadIdx.x;
  float v = (raw_sum[t] * (1.f/(float)NN)) * (cnt1[t] * (1.f/(float)NN));
  v += __shfl_down(v, 32); v += __shfl_down(v, 16); v += __shfl_down(v, 8);
  v += __shfl_down(v, 4);  v += __shfl_down(v, 2);  v += __shfl_down(v, 1);
  __shared__ float r2[2];
  if ((t & 63) == 0) r2[t >> 6] = v;
  __syncthreads();
  if (t == 0)
    out_loss[0] = (r2[0] + r2[1]) * ((float)(EE*EE) / (float)(BB*EE)) * 0.01f;
}

// ---------------------------------------------------------------- q = audio@Wq, r[d][h] = Wk-row·q_head  (per e,b)
__global__ __launch_bounds__(256) void qr_kernel(
    const float* __restrict__ audio, const float* __restrict__ Wq,
    const float* __restrict__ Wkv, float* __restrict__ rws)
{
  __shared__ float aS[DD];
  __shared__ float qS[DD];
  int tid = threadIdx.x, eb = blockIdx.x, e = eb >> 3, b = eb & 7;
  aS[tid] = audio[b*DD + tid];
  __syncthreads();
  const float* w = Wq + (size_t)e * DD * DD;
  float acc = 0.f;
#pragma unroll 4
  for (int k = 0; k < DD; ++k) acc += aS[k] * w[(size_t)k*DD + tid];
  qS[tid] = acc;
  __syncthreads();
  // r[d][h] = sum_{j<32} Wkv[e][d][h*32+j] * q[h*32+j]   (k-half: cols 0..255)
  int wave = tid >> 6, lane = tid & 63;
  const float* wk = Wkv + (size_t)e * (DD*2*DD);
  float4 qv = *(const float4*)(qS + lane*4);
  int h = lane >> 3;
  float* rout = rws + (size_t)eb * (DD*HH);
  for (int i = 0; i < 64; ++i) {
    int d = wave*64 + i;
    float4 wv = *(const float4*)(wk + (size_t)d*(2*DD) + lane*4);
    float p = wv.x*qv.x + wv.y*qv.y + wv.z*qv.z + wv.w*qv.w;
    p += __shfl_down(p, 4);
    p += __shfl_down(p, 2);
    p += __shfl_down(p, 1);
    if ((lane & 7) == 0) rout[d*HH + h] = p;
  }
}

// ---------------------------------------------------------------- logits -> softmax -> xattn = attn @ Xslot  (per e,b)
__global__ __launch_bounds__(256) void attnx_kernel(
    const float* __restrict__ x, const float* __restrict__ rws,
    const int* __restrict__ slot_token, float* __restrict__ xattn)
{
  __shared__ float rS[DD][HH];      // 8 KB
  __shared__ float lS[CAPC][9];     // 9 KB, pad->9 for conflict-free col reads
  __shared__ float aS[HH][CAPC];    // 8 KB
  __shared__ int   tokS[CAPC];
  __shared__ float smx[HH], sden[HH];
  int tid = threadIdx.x, eb = blockIdx.x;
  int wave = tid >> 6, lane = tid & 63;
  const float* rin = rws + (size_t)eb * (DD*HH);
  for (int t = tid; t < DD*HH; t += 256) ((float*)rS)[t] = rin[t];
  int token = slot_token[eb*CAPC + tid];
  tokS[tid] = token;
  __syncthreads();
  // phase A: logits (thread = slot)
  float l[HH];
#pragma unroll
  for (int h = 0; h < HH; ++h) l[h] = 0.f;
  if (token >= 0) {
    const float4* xr = (const float4*)(x + (size_t)token * DD);
    for (int d4 = 0; d4 < DD/4; ++d4) {
      float4 xv = xr[d4];
      float xa[4] = {xv.x, xv.y, xv.z, xv.w};
#pragma unroll
      for (int dd = 0; dd < 4; ++dd) {
        int d = d4*4 + dd;
        float4 r0 = *(const float4*)&rS[d][0];
        float4 r1 = *(const float4*)&rS[d][4];
        float xc = xa[dd];
        l[0] += xc*r0.x; l[1] += xc*r0.y; l[2] += xc*r0.z; l[3] += xc*r0.w;
        l[4] += xc*r1.x; l[5] += xc*r1.y; l[6] += xc*r1.z; l[7] += xc*r1.w;
      }
    }
#pragma unroll
    for (int h = 0; h < HH; ++h) l[h] *= 0.17677669529663687f;  // 32^-0.5
  }
#pragma unroll
  for (int h = 0; h < HH; ++h) lS[tid][h] = l[h];
  __syncthreads();
  // softmax over slots per head; wave w reduces h=w and h=w+4
#pragma unroll
  for (int hh = 0; hh < 2; ++hh) {
    int h = wave + hh*4;
    float m = fmaxf(fmaxf(lS[lane][h], lS[lane+64][h]),
                    fmaxf(lS[lane+128][h], lS[lane+192][h]));
    m = fmaxf(m, __shfl_down(m,32)); m = fmaxf(m, __shfl_down(m,16));
    m = fmaxf(m, __shfl_down(m,8));  m = fmaxf(m, __shfl_down(m,4));
    m = fmaxf(m, __shfl_down(m,2));  m = fmaxf(m, __shfl_down(m,1));
    if (lane == 0) smx[h] = m;
  }
  __syncthreads();
  float ex[HH];
#pragma unroll
  for (int h = 0; h < HH; ++h) { ex[h] = expf(l[h] - smx[h]); lS[tid][h] = ex[h]; }
  __syncthreads();
#pragma unroll
  for (int hh = 0; hh < 2; ++hh) {
    int h = wave + hh*4;
    float s = lS[lane][h] + lS[lane+64][h] + lS[lane+128][h] + lS[lane+192][h];
    s += __shfl_down(s,32); s += __shfl_down(s,16); s += __shfl_down(s,8);
    s += __shfl_down(s,4);  s += __shfl_down(s,2);  s += __shfl_down(s,1);
    if (lane == 0) sden[h] = s;
  }
  __syncthreads();
#pragma unroll
  for (int h = 0; h < HH; ++h) aS[h][tid] = ex[h] / sden[h];
  __syncthreads();
  // phase B: xattn[h][d=tid] = sum_s a[h][s] * x[token_s][tid]
  float acc[HH];
#pragma unroll
  for (int h = 0; h < HH; ++h) acc[h] = 0.f;
  for (int s4 = 0; s4 < CAPC/4; ++s4) {
    float av[HH][4];
#pragma unroll
    for (int h = 0; h < HH; ++h) {
      float4 a4 = *(const float4*)&aS[h][s4*4];
      av[h][0]=a4.x; av[h][1]=a4.y; av[h][2]=a4.z; av[h][3]=a4.w;
    }
#pragma unroll
    for (int i = 0; i < 4; ++i) {
      int tk = tokS[s4*4+i];     // wave-uniform
      if (tk >= 0) {
        float xv = x[(size_t)tk*DD + tid];
#pragma unroll
        for (int h = 0; h < HH; ++h) acc[h] += av[h][i] * xv;
      }
    }
  }
  float* xo = xattn + (size_t)eb*(HH*DD);
#pragma unroll
  for (int h = 0; h < HH; ++h) xo[h*DD + tid] = acc[h];
}

// ---------------------------------------------------------------- o = xattn@Wv ; gate = sigmoid(o@Wp+bp)  (per e,b)
__global__ __launch_bounds__(256) void ogate_kernel(
    const float* __restrict__ xattn, const float* __restrict__ Wkv,
    const float* __restrict__ Wp, const float* __restrict__ bp,
    float* __restrict__ gateW)
{
  __shared__ float xaS[HH*DD];   // [h][d]
  __shared__ float oS[DD];
  int tid = threadIdx.x, eb = blockIdx.x, e = eb >> 3;
  const float* xi = xattn + (size_t)eb*(HH*DD);
  for (int t = tid; t < HH*DD; t += 256) xaS[t] = xi[t];
  __syncthreads();
  int h = tid >> 5;
  // o[c=tid] = sum_d xattn[h][d] * Wv[e][d][256 + tid]   (v-cols are 256..511)
  const float* wv = Wkv + (size_t)e*(DD*2*DD) + DD + tid;
  float acc = 0.f;
#pragma unroll 4
  for (int d = 0; d < DD; ++d)
    acc += xaS[h*DD + d] * wv[(size_t)d*(2*DD)];
  oS[tid] = acc;
  __syncthreads();
  const float* wp = Wp + (size_t)e*DD*DD + tid;
  float s = bp[e*DD + tid];
#pragma unroll 4
  for (int c = 0; c < DD; ++c)
    s += oS[c] * wp[(size_t)c*DD];
  gateW[(size_t)eb*DD + tid] = 1.f/(1.f + expf(-s));
}

// ---------------------------------------------------------------- recombine (float4)
__global__ __launch_bounds__(256) void out_kernel(
    const float* __restrict__ x, const float* __restrict__ g1f, const float* __restrict__ g2f,
    const int* __restrict__ idx1a, const int* __restrict__ idx2a,
    const float* __restrict__ gateW, float* __restrict__ out)
{
  int idx = blockIdx.x*256 + threadIdx.x;   // float4 index
  int token = idx >> 6;
  int d4 = idx & 63;
  int b = token >> 11;
  float g1 = g1f[token], g2 = g2f[token];
  int e1 = idx1a[token], e2 = idx2a[token];
  float4 w1 = ((const float4*)(gateW + (size_t)(e1*BB+b)*DD))[d4];
  float4 w2 = ((const float4*)(gateW + (size_t)(e2*BB+b)*DD))[d4];
  float4 xv = ((const float4*)x)[idx];
  float4 o;
  o.x = xv.x*(g1*w1.x + g2*w2.x);
  o.y = xv.y*(g1*w1.y + g2*w2.y);
  o.z = xv.z*(g1*w1.z + g2*w2.z);
  o.w = xv.w*(g1*w1.w + g2*w2.w);
  ((float4*)out)[idx] = o;
}

// ---------------------------------------------------------------- launcher
extern "C" void kernel_launch(void* const* d_in, const int* in_sizes, int n_in,
                              void* d_out, int out_size, void* d_ws, size_t ws_size,
                              hipStream_t stream)
{
  const float* x     = (const float*)d_in[0];
  const float* audio = (const float*)d_in[1];
  const float* wg    = (const float*)d_in[2];
  const float* Wq    = (const float*)d_in[3];
  const float* Wkv   = (const float*)d_in[4];
  const float* Wp    = (const float*)d_in[5];
  const float* bp    = (const float*)d_in[6];
  float* out = (float*)d_out;

  // workspace (~2.7 MB)
  float* raw_sum = (float*)d_ws;                       // 128
  float* cnt1    = raw_sum + 128;                      // 128
  int*   idx1a   = (int*)(cnt1 + 128);                 // BN
  int*   idx2a   = idx1a + BN;                         // BN
  float* g1a     = (float*)(idx2a + BN);               // BN
  float* g2a     = g1a + BN;                           // BN
  float* g1f     = g2a + BN;                           // BN
  float* g2f     = g1f + BN;                           // BN
  int*   slot_token = (int*)(g2f + BN);                // EB*CAP = 32768
  float* rws     = (float*)(slot_token + EB*CAPC);     // EB*D*H = 262144
  float* xattn   = rws + (size_t)EB*DD*HH;             // EB*H*D = 262144
  float* gateW   = xattn + (size_t)EB*HH*DD;           // EB*D   = 32768

  hipMemsetAsync(raw_sum, 0, 256*sizeof(float), stream);
  hipMemsetAsync(slot_token, 0xFF, (size_t)EB*CAPC*sizeof(int), stream);  // -1

  gating_kernel<<<BN/256, 256, 0, stream>>>(x, wg, idx1a, idx2a, g1a, g2a, raw_sum, cnt1);
  scan_kernel<<<BB, 256, 0, stream>>>(idx1a, idx2a, g1a, g2a, g1f, g2f, slot_token);
  loss_kernel<<<1, 128, 0, stream>>>(raw_sum, cnt1, out + (size_t)out_size - 1);
  qr_kernel<<<EB, 256, 0, stream>>>(audio, Wq, Wkv, rws);
  attnx_kernel<<<EB, 256, 0, stream>>>(x, rws, slot_token, xattn);
  ogate_kernel<<<EB, 256, 0, stream>>>(xattn, Wkv, Wp, bp, gateW);
  out_kernel<<<(BN*DD/4)/256, 256, 0, stream>>>(x, g1f, g2f, idx1a, idx2a, gateW, out);
}

// Round 3
// 187.265 us; speedup vs baseline: 1.9866x; 1.5653x over previous
//
#include <hip/hip_runtime.h>
#include <cstdint>
#include <cstddef>

#define BB 8
#define NN 2048
#define DD 256
#define EE 16
#define HH 8
#define CAPC 256
#define BN (BB*NN)   // 16384
#define EB (EE*BB)   // 128

// ---------------------------------------------------------------- gating (64 tokens/block, 4 k-chunks)
__global__ __launch_bounds__(256) void gating_kernel(
    const float* __restrict__ x, const float* __restrict__ wg,
    int* __restrict__ idx1a, int* __restrict__ idx2a,
    float* __restrict__ g1a, float* __restrict__ g2a,
    float* __restrict__ raw_sum, float* __restrict__ cnt1)
{
  __shared__ float wgS[DD*EE];        // 16 KB
  __shared__ float lgp[4][64][17];    // 17.4 KB (pad 17 vs 16: conflict-free col reads)
  int tid = threadIdx.x;
  for (int t = tid; t < DD*EE; t += 256) wgS[t] = wg[t];
  __syncthreads();
  int tk = tid & 63, kc = tid >> 6;
  int token0 = blockIdx.x * 64;
  int token = token0 + tk;
  const float4* xr = (const float4*)(x + (size_t)token*DD + kc*64);
  const float4* wg4 = (const float4*)wgS;
  float lg[16];
#pragma unroll
  for (int e = 0; e < 16; ++e) lg[e] = 0.f;
#pragma unroll
  for (int d4 = 0; d4 < 16; ++d4) {
    float4 xv = xr[d4];
    float xa[4] = {xv.x, xv.y, xv.z, xv.w};
#pragma unroll
    for (int dd = 0; dd < 4; ++dd) {
      int d = kc*64 + d4*4 + dd;
      float xc = xa[dd];
#pragma unroll
      for (int j = 0; j < 4; ++j) {
        float4 w = wg4[d*4 + j];
        lg[4*j+0] += xc*w.x; lg[4*j+1] += xc*w.y;
        lg[4*j+2] += xc*w.z; lg[4*j+3] += xc*w.w;
      }
    }
  }
#pragma unroll
  for (int e = 0; e < 16; ++e) lgp[kc][tk][e] = lg[e];
  __syncthreads();
  if (tid < 64) {     // wave 0 finalizes 64 tokens
    int lane = tid;
    float l[16];
#pragma unroll
    for (int e = 0; e < 16; ++e)
      l[e] = lgp[0][lane][e] + lgp[1][lane][e] + lgp[2][lane][e] + lgp[3][lane][e];
    float mx = l[0];
#pragma unroll
    for (int e = 1; e < 16; ++e) mx = fmaxf(mx, l[e]);
    float p[16]; float s = 0.f;
#pragma unroll
    for (int e = 0; e < 16; ++e) { p[e] = expf(l[e] - mx); s += p[e]; }
    int i1 = 0; float b1 = p[0];
#pragma unroll
    for (int e = 1; e < 16; ++e) { if (p[e] > b1) { b1 = p[e]; i1 = e; } }
    float b2 = (i1 == 0) ? 0.f : p[0]; int i2 = 0;
#pragma unroll
    for (int e = 1; e < 16; ++e) { float v = (e == i1) ? 0.f : p[e]; if (v > b2) { b2 = v; i2 = e; } }
    float inv = 1.f / s;
    float g1 = b1*inv, g2 = b2*inv;
    float den = g1 + g2 + 1e-9f;
    g1 /= den; g2 /= den;
    int tok = token0 + lane;
    idx1a[tok] = i1; idx2a[tok] = i2;
    g1a[tok] = g1;   g2a[tok] = g2;
    int b = tok >> 11;
#pragma unroll
    for (int e = 0; e < 16; ++e) {
      float v = p[e] * inv;
      v += __shfl_down(v, 32); v += __shfl_down(v, 16);
      v += __shfl_down(v, 8);  v += __shfl_down(v, 4);
      v += __shfl_down(v, 2);  v += __shfl_down(v, 1);
      unsigned long long mb = __ballot(i1 == e);
      if (lane == 0) {
        atomicAdd(&raw_sum[b*16 + e], v);
        atomicAdd(&cnt1[b*16 + e], (float)__popcll(mb));
      }
    }
  }
}

// ---------------------------------------------------------------- position scan (per batch) + loss in block 0
__global__ __launch_bounds__(256) void scan_kernel(
    const int* __restrict__ idx1a, const int* __restrict__ idx2a,
    float* __restrict__ g1a, float* __restrict__ g2a, int* __restrict__ slot_token,
    const float* __restrict__ raw_sum, const float* __restrict__ cnt1,
    float* __restrict__ out_loss)
{
  __shared__ unsigned long long m1s[16][32], m2s[16][32];
  __shared__ int wp1[16][32], wp2[16][32], mcnt[16];
  int b = blockIdx.x, tid = threadIdx.x;
  int wave = tid >> 6, lane = tid & 63;
  for (int w = wave; w < 32; w += 4) {
    int token = b*NN + w*64 + lane;
    int i1 = idx1a[token], i2 = idx2a[token];
#pragma unroll
    for (int e = 0; e < 16; ++e) {
      unsigned long long ma = __ballot(i1 == e);
      unsigned long long mb = __ballot(i2 == e);
      if (lane == 0) { m1s[e][w] = ma; m2s[e][w] = mb; }
    }
  }
  __syncthreads();
  if (tid < 16) {
    int run = 0;
    for (int w = 0; w < 32; ++w) { wp1[tid][w] = run; run += (int)__popcll(m1s[tid][w]); }
    mcnt[tid] = run < CAPC ? run : CAPC;
  } else if (tid < 32) {
    int e2 = tid - 16; int run = 0;
    for (int w = 0; w < 32; ++w) { wp2[e2][w] = run; run += (int)__popcll(m2s[e2][w]); }
  }
  __syncthreads();
  for (int w = wave; w < 32; w += 4) {
    int token = b*NN + w*64 + lane;
    int i1 = idx1a[token], i2 = idx2a[token];
    unsigned long long lt = (1ull << lane) - 1ull;
    int pos1 = wp1[i1][w] + (int)__popcll(m1s[i1][w] & lt);
    float g1 = g1a[token];
    bool k1 = pos1 < CAPC;
    g1a[token] = k1 ? g1 : 0.f;
    if (k1) slot_token[(i1*BB + b)*CAPC + pos1] = token;
    int pos2 = mcnt[i2] + wp2[i2][w] + (int)__popcll(m2s[i2][w] & lt);
    float g2 = g2a[token];
    bool k2 = pos2 < CAPC;
    g2a[token] = k2 ? g2 : 0.f;
    if (k2 && g2 > 0.f) slot_token[(i2*BB + b)*CAPC + pos2] = token;
  }
  // ---- loss (raw_sum/cnt1 are complete: gating finished before this kernel)
  if (blockIdx.x == 0) {
    float v = 0.f;
    if (tid < 128) v = (raw_sum[tid] * (1.f/(float)NN)) * (cnt1[tid] * (1.f/(float)NN));
    v += __shfl_down(v, 32); v += __shfl_down(v, 16); v += __shfl_down(v, 8);
    v += __shfl_down(v, 4);  v += __shfl_down(v, 2);  v += __shfl_down(v, 1);
    __shared__ float r4[4];
    if ((tid & 63) == 0) r4[tid >> 6] = v;
    __syncthreads();
    if (tid == 0)
      out_loss[0] = (r4[0]+r4[1]+r4[2]+r4[3]) * ((float)(EE*EE) / (float)(BB*EE)) * 0.01f;
  }
}

// ---------------------------------------------------------------- q (all b) + r = Wk·q  per (e,h)
__global__ __launch_bounds__(256) void qr_kernel(
    const float* __restrict__ audio, const float* __restrict__ Wq,
    const float* __restrict__ Wkv, float* __restrict__ rws)
{
  __shared__ float aS[DD][8];        // audio [k][b]  8 KB
  __shared__ float qpart[8][32][9];  // 9.2 KB
  __shared__ float qS[32][8];        // 1 KB
  __shared__ float wkS[DD][33];      // 33.8 KB
  int tid = threadIdx.x;
  int e = blockIdx.x >> 3, h = blockIdx.x & 7;
  for (int i = tid; i < 2048; i += 256) { int b = i >> 8, k = i & 255; aS[k][b] = audio[b*DD + k]; }
  __syncthreads();
  // q[b][j] partials: thread (j, kg)
  int j = tid & 31, kg = tid >> 5;
  const float* wq = Wq + (size_t)e*DD*DD + h*32 + j;
  float acc[8] = {0,0,0,0,0,0,0,0};
#pragma unroll
  for (int i = 0; i < 32; ++i) {
    int k = kg*32 + i;
    float w = wq[(size_t)k*DD];
    float4 a0 = *(const float4*)&aS[k][0];
    float4 a1 = *(const float4*)&aS[k][4];
    acc[0]+=w*a0.x; acc[1]+=w*a0.y; acc[2]+=w*a0.z; acc[3]+=w*a0.w;
    acc[4]+=w*a1.x; acc[5]+=w*a1.y; acc[6]+=w*a1.z; acc[7]+=w*a1.w;
  }
#pragma unroll
  for (int b = 0; b < 8; ++b) qpart[kg][j][b] = acc[b];
  // stage Wk slice (independent of qpart)
  const float* wkbase = Wkv + (size_t)e*(DD*2*DD) + h*32;
  float4 stg[8];
#pragma unroll
  for (int m = 0; m < 8; ++m) {
    int row = m*32 + (tid >> 3), c4 = tid & 7;
    stg[m] = *(const float4*)(wkbase + (size_t)row*(2*DD) + c4*4);
  }
#pragma unroll
  for (int m = 0; m < 8; ++m) {
    int row = m*32 + (tid >> 3), c4 = tid & 7;
    wkS[row][c4*4+0] = stg[m].x; wkS[row][c4*4+1] = stg[m].y;
    wkS[row][c4*4+2] = stg[m].z; wkS[row][c4*4+3] = stg[m].w;
  }
  __syncthreads();
  {  // reduce q partials: thread -> (j, b)
    int jj = tid >> 3, b = tid & 7;
    float s = 0.f;
#pragma unroll
    for (int g = 0; g < 8; ++g) s += qpart[g][jj][b];
    qS[jj][b] = s;
  }
  __syncthreads();
  // r[b][d] = sum_j wkS[d][j] * qS[j][b] ; thread = d
  int d = tid;
  float racc[8] = {0,0,0,0,0,0,0,0};
#pragma unroll
  for (int jj = 0; jj < 32; ++jj) {
    float w = wkS[d][jj];
    float4 q0 = *(const float4*)&qS[jj][0];
    float4 q1 = *(const float4*)&qS[jj][4];
    racc[0]+=w*q0.x; racc[1]+=w*q0.y; racc[2]+=w*q0.z; racc[3]+=w*q0.w;
    racc[4]+=w*q1.x; racc[5]+=w*q1.y; racc[6]+=w*q1.z; racc[7]+=w*q1.w;
  }
#pragma unroll
  for (int b = 0; b < 8; ++b)
    rws[((size_t)(e*8 + b))*2048 + d*8 + h] = racc[b];
}

// ---------------------------------------------------------------- per-slot logits (slot-parallel)
__global__ __launch_bounds__(256) void lslot_kernel(
    const float* __restrict__ x, const float* __restrict__ rws,
    const int* __restrict__ slot_token, float* __restrict__ lslot)
{
  __shared__ float rS[DD][8];     // 8 KB  [d][h]
  __shared__ float lp[128][17];   // 8.5 KB
  int tid = threadIdx.x;
  int eb = blockIdx.x >> 1, half = blockIdx.x & 1;
  {
    const float4* rin = (const float4*)(rws + (size_t)eb*2048);
    float4* rS4 = (float4*)rS;
    rS4[tid] = rin[tid]; rS4[tid+256] = rin[tid+256];
  }
  int s = tid & 127, kc = tid >> 7;
  int slot = half*128 + s;
  int token = slot_token[eb*CAPC + slot];
  __syncthreads();
  float l[8] = {0,0,0,0,0,0,0,0};
  if (token >= 0) {
    const float4* xr = (const float4*)(x + (size_t)token*DD + kc*128);
#pragma unroll
    for (int d4 = 0; d4 < 32; ++d4) {
      float4 xv = xr[d4];
      float xa[4] = {xv.x, xv.y, xv.z, xv.w};
#pragma unroll
      for (int dd = 0; dd < 4; ++dd) {
        int d = kc*128 + d4*4 + dd;
        float4 r0 = *(const float4*)&rS[d][0];
        float4 r1 = *(const float4*)&rS[d][4];
        float xc = xa[dd];
        l[0]+=xc*r0.x; l[1]+=xc*r0.y; l[2]+=xc*r0.z; l[3]+=xc*r0.w;
        l[4]+=xc*r1.x; l[5]+=xc*r1.y; l[6]+=xc*r1.z; l[7]+=xc*r1.w;
      }
    }
  }
#pragma unroll
  for (int hh = 0; hh < 8; ++hh) lp[s][kc*8 + hh] = l[hh];
  __syncthreads();
  int s2 = tid & 127, hg = (tid >> 7)*4;
  float4 o4;
  o4.x = (lp[s2][hg+0] + lp[s2][8+hg+0]) * 0.17677669529663687f;
  o4.y = (lp[s2][hg+1] + lp[s2][8+hg+1]) * 0.17677669529663687f;
  o4.z = (lp[s2][hg+2] + lp[s2][8+hg+2]) * 0.17677669529663687f;
  o4.w = (lp[s2][hg+3] + lp[s2][8+hg+3]) * 0.17677669529663687f;
  *(float4*)(lslot + ((size_t)eb*CAPC + half*128 + s2)*8 + hg) = o4;
}

// ---------------------------------------------------------------- softmax + xattn = attn @ Xslot  per (eb, d-half)
__global__ __launch_bounds__(256) void attnx_kernel(
    const float* __restrict__ x, const float* __restrict__ lslot,
    const int* __restrict__ slot_token, float* __restrict__ xattn)
{
  __shared__ float lS[CAPC][9];        // 9 KB
  __shared__ float aS[HH][CAPC];       // 8 KB
  __shared__ float part[2][HH][128];   // 8 KB
  __shared__ int tokS[CAPC];
  __shared__ float red[16];
  int tid = threadIdx.x;
  int eb = blockIdx.x >> 1, dh = blockIdx.x & 1;
  int d0 = dh*128;
  {
    const float4* li = (const float4*)(lslot + (size_t)eb*CAPC*8);
    float4 v0 = li[tid*2], v1 = li[tid*2+1];
    lS[tid][0]=v0.x; lS[tid][1]=v0.y; lS[tid][2]=v0.z; lS[tid][3]=v0.w;
    lS[tid][4]=v1.x; lS[tid][5]=v1.y; lS[tid][6]=v1.z; lS[tid][7]=v1.w;
    tokS[tid] = slot_token[eb*CAPC + tid];
  }
  __syncthreads();
  int lane = tid & 63, wave = tid >> 6;
#pragma unroll
  for (int r = 0; r < 2; ++r) {
    int hh = wave + r*4;
    float m = fmaxf(fmaxf(lS[lane][hh], lS[lane+64][hh]),
                    fmaxf(lS[lane+128][hh], lS[lane+192][hh]));
    m = fmaxf(m, __shfl_down(m,32)); m = fmaxf(m, __shfl_down(m,16));
    m = fmaxf(m, __shfl_down(m,8));  m = fmaxf(m, __shfl_down(m,4));
    m = fmaxf(m, __shfl_down(m,2));  m = fmaxf(m, __shfl_down(m,1));
    if (lane == 0) red[hh] = m;
  }
  __syncthreads();
  float ex[8];
#pragma unroll
  for (int h = 0; h < 8; ++h) { ex[h] = expf(lS[tid][h] - red[h]); aS[h][tid] = ex[h]; }
  __syncthreads();
#pragma unroll
  for (int r = 0; r < 2; ++r) {
    int hh = wave + r*4;
    float ssum = aS[hh][lane] + aS[hh][lane+64] + aS[hh][lane+128] + aS[hh][lane+192];
    ssum += __shfl_down(ssum,32); ssum += __shfl_down(ssum,16); ssum += __shfl_down(ssum,8);
    ssum += __shfl_down(ssum,4);  ssum += __shfl_down(ssum,2);  ssum += __shfl_down(ssum,1);
    if (lane == 0) red[8+hh] = ssum;
  }
  __syncthreads();
#pragma unroll
  for (int h = 0; h < 8; ++h) aS[h][tid] = ex[h] / red[8+h];
  __syncthreads();
  // phase B: thread (d, sc); 128 slots each; masked unconditional loads
  int d = tid & 127, sc = tid >> 7;
  int dcol = d0 + d;
  float acc[8] = {0,0,0,0,0,0,0,0};
#pragma unroll 8
  for (int i = 0; i < 128; ++i) {
    int s = sc*128 + i;
    int tk = tokS[s];
    int tkc = tk < 0 ? 0 : tk;
    float msk = tk < 0 ? 0.f : 1.f;
    float xv = x[(size_t)tkc*DD + dcol] * msk;
#pragma unroll
    for (int h = 0; h < 8; ++h) acc[h] += aS[h][s] * xv;
  }
#pragma unroll
  for (int h = 0; h < 8; ++h) part[sc][h][d] = acc[h];
  __syncthreads();
  int d2 = tid & 127; int hg = (tid >> 7)*4;
#pragma unroll
  for (int i = 0; i < 4; ++i) {
    int h = hg + i;
    xattn[(size_t)eb*2048 + h*DD + d0 + d2] = part[0][h][d2] + part[1][h][d2];
  }
}

// ---------------------------------------------------------------- o = xattn @ Wv  per (e, 32-col chunk)
__global__ __launch_bounds__(256) void o_kernel(
    const float* __restrict__ xattn, const float* __restrict__ Wkv,
    float* __restrict__ o_ws)
{
  __shared__ float xaS[8][DD];       // 8 KB [b][d] for this h
  __shared__ float op[8][32][9];     // 9.2 KB
  int tid = threadIdx.x;
  int e = blockIdx.x >> 3, ch = blockIdx.x & 7;
  int c0 = ch*32, h = ch;
  for (int i = tid; i < 2048; i += 256) {
    int b = i >> 8, d = i & 255;
    xaS[b][d] = xattn[((size_t)(e*8 + b))*2048 + h*DD + d];
  }
  __syncthreads();
  int c = tid & 31, kc = tid >> 5;
  const float* wv = Wkv + (size_t)e*(DD*2*DD) + DD + c0 + c;
  float acc[8] = {0,0,0,0,0,0,0,0};
#pragma unroll
  for (int i = 0; i < 32; ++i) {
    int d = kc*32 + i;
    float w = wv[(size_t)d*(2*DD)];
#pragma unroll
    for (int b = 0; b < 8; ++b) acc[b] += w * xaS[b][d];
  }
#pragma unroll
  for (int b = 0; b < 8; ++b) op[kc][c][b] = acc[b];
  __syncthreads();
  int c2 = tid & 31, b2 = tid >> 5;
  float s = 0.f;
#pragma unroll
  for (int g = 0; g < 8; ++g) s += op[g][c2][b2];
  o_ws[((size_t)(e*8 + b2))*DD + c0 + c2] = s;
}

// ---------------------------------------------------------------- gate = sigmoid(o @ Wp + bp)  per (e, 32-col chunk)
__global__ __launch_bounds__(256) void gate_kernel(
    const float* __restrict__ o_ws, const float* __restrict__ Wp,
    const float* __restrict__ bp, float* __restrict__ gateW)
{
  __shared__ float oS[8][DD];        // 8 KB
  __shared__ float op[8][32][9];
  int tid = threadIdx.x;
  int e = blockIdx.x >> 3, ch = blockIdx.x & 7;
  int c0 = ch*32;
  for (int i = tid; i < 2048; i += 256) {
    int b = i >> 8, d = i & 255;
    oS[b][d] = o_ws[((size_t)(e*8 + b))*DD + d];
  }
  __syncthreads();
  int c = tid & 31, kc = tid >> 5;
  const float* wp = Wp + (size_t)e*DD*DD + c0 + c;
  float acc[8] = {0,0,0,0,0,0,0,0};
#pragma unroll
  for (int i = 0; i < 32; ++i) {
    int d = kc*32 + i;
    float w = wp[(size_t)d*DD];
#pragma unroll
    for (int b = 0; b < 8; ++b) acc[b] += w * oS[b][d];
  }
#pragma unroll
  for (int b = 0; b < 8; ++b) op[kc][c][b] = acc[b];
  __syncthreads();
  int c2 = tid & 31, b2 = tid >> 5;
  float s = bp[e*DD + c0 + c2];
#pragma unroll
  for (int g = 0; g < 8; ++g) s += op[g][c2][b2];
  gateW[((size_t)(e*8 + b2))*DD + c0 + c2] = 1.f / (1.f + expf(-s));
}

// ---------------------------------------------------------------- recombine (float4)
__global__ __launch_bounds__(256) void out_kernel(
    const float* __restrict__ x, const float* __restrict__ g1f, const float* __restrict__ g2f,
    const int* __restrict__ idx1a, const int* __restrict__ idx2a,
    const float* __restrict__ gateW, float* __restrict__ out)
{
  int idx = blockIdx.x*256 + threadIdx.x;   // float4 index
  int token = idx >> 6;
  int d4 = idx & 63;
  int b = token >> 11;
  float g1 = g1f[token], g2 = g2f[token];
  int e1 = idx1a[token], e2 = idx2a[token];
  float4 w1 = ((const float4*)(gateW + (size_t)(e1*BB+b)*DD))[d4];
  float4 w2 = ((const float4*)(gateW + (size_t)(e2*BB+b)*DD))[d4];
  float4 xv = ((const float4*)x)[idx];
  float4 o;
  o.x = xv.x*(g1*w1.x + g2*w2.x);
  o.y = xv.y*(g1*w1.y + g2*w2.y);
  o.z = xv.z*(g1*w1.z + g2*w2.z);
  o.w = xv.w*(g1*w1.w + g2*w2.w);
  ((float4*)out)[idx] = o;
}

// ---------------------------------------------------------------- launcher
extern "C" void kernel_launch(void* const* d_in, const int* in_sizes, int n_in,
                              void* d_out, int out_size, void* d_ws, size_t ws_size,
                              hipStream_t stream)
{
  const float* x     = (const float*)d_in[0];
  const float* audio = (const float*)d_in[1];
  const float* wg    = (const float*)d_in[2];
  const float* Wq    = (const float*)d_in[3];
  const float* Wkv   = (const float*)d_in[4];
  const float* Wp    = (const float*)d_in[5];
  const float* bp    = (const float*)d_in[6];
  float* out = (float*)d_out;

  // workspace (~3.6 MB with aliasing)
  float* raw_sum = (float*)d_ws;                       // 128
  float* cnt1    = raw_sum + 128;                      // 128
  int*   idx1a   = (int*)(cnt1 + 128);                 // BN
  int*   idx2a   = idx1a + BN;                         // BN
  float* g1a     = (float*)(idx2a + BN);               // BN  (scan truncates in place)
  float* g2a     = g1a + BN;                           // BN
  int*   slot_token = (int*)(g2a + BN);                // EB*CAP = 32768
  float* rws     = (float*)(slot_token + EB*CAPC);     // EB*2048 = 262144
  float* lslot   = rws + (size_t)EB*2048;              // EB*CAP*8 = 262144
  float* xattn   = lslot + (size_t)EB*CAPC*8;          // EB*2048 = 262144
  float* o_ws    = rws;                                // alias: rws dead after lslot_kernel... (last read: lslot)
  float* gateW   = lslot;                              // alias: lslot dead after attnx_kernel

  hipMemsetAsync(raw_sum, 0, 256*sizeof(float), stream);
  hipMemsetAsync(slot_token, 0xFF, (size_t)EB*CAPC*sizeof(int), stream);  // -1

  qr_kernel  <<<EB, 256, 0, stream>>>(audio, Wq, Wkv, rws);
  gating_kernel<<<BN/64, 256, 0, stream>>>(x, wg, idx1a, idx2a, g1a, g2a, raw_sum, cnt1);
  scan_kernel<<<BB, 256, 0, stream>>>(idx1a, idx2a, g1a, g2a, slot_token,
                                      raw_sum, cnt1, out + (size_t)out_size - 1);
  lslot_kernel<<<EB*2, 256, 0, stream>>>(x, rws, slot_token, lslot);
  attnx_kernel<<<EB*2, 256, 0, stream>>>(x, lslot, slot_token, xattn);
  o_kernel   <<<EB, 256, 0, stream>>>(xattn, Wkv, o_ws);
  gate_kernel<<<EB, 256, 0, stream>>>(o_ws, Wp, bp, gateW);
  out_kernel <<<(BN*DD/4)/256, 256, 0, stream>>>(x, g1a, g2a, idx1a, idx2a, gateW, out);
}

// Round 4
// 162.566 us; speedup vs baseline: 2.2884x; 1.1519x over previous
//
#include <hip/hip_runtime.h>
#include <cstdint>
#include <cstddef>

#define BB 8
#define NN 2048
#define DD 256
#define EE 16
#define HH 8
#define CAPC 256
#define BN (BB*NN)   // 16384
#define EB (EE*BB)   // 128

// ================================================================ kernel 1:
// blocks 0..255   : gating (64 tokens each), per-block loss partials (no atomics)
// blocks 256..383 : qr per (e,h): q[b]=audio[b]@Wq[e]; r[b][d]=Wk[e][d,h*32:]·q_head
__global__ __launch_bounds__(256) void fused_gq_kernel(
    const float* __restrict__ x, const float* __restrict__ wg,
    const float* __restrict__ audio, const float* __restrict__ Wq,
    const float* __restrict__ Wkv,
    int* __restrict__ idx1a, int* __restrict__ idx2a,
    float* __restrict__ g1a, float* __restrict__ g2a,
    float* __restrict__ raw_part, float* __restrict__ cnt_part,
    float* __restrict__ rws)
{
  __shared__ union SM {
    struct { float wgS[DD*EE]; float lgp[4][64][17]; } g;                     // 33.4 KB
    struct { float aS[DD][8]; float qpart[8][32][9]; float qS[32][8];
             float wkS[DD][33]; } q;                                          // 52 KB
  } sm;
  int tid = threadIdx.x;

  if (blockIdx.x < 256) {
    // ---------------- gating ----------------
    for (int t = tid; t < DD*EE; t += 256) sm.g.wgS[t] = wg[t];
    __syncthreads();
    int tk = tid & 63, kc = tid >> 6;
    int token0 = blockIdx.x * 64;
    int token = token0 + tk;
    const float4* xr = (const float4*)(x + (size_t)token*DD + kc*64);
    const float4* wg4 = (const float4*)sm.g.wgS;
    float lg[16];
#pragma unroll
    for (int e = 0; e < 16; ++e) lg[e] = 0.f;
#pragma unroll
    for (int d4 = 0; d4 < 16; ++d4) {
      float4 xv = xr[d4];
      float xa[4] = {xv.x, xv.y, xv.z, xv.w};
#pragma unroll
      for (int dd = 0; dd < 4; ++dd) {
        int d = kc*64 + d4*4 + dd;
        float xc = xa[dd];
#pragma unroll
        for (int j = 0; j < 4; ++j) {
          float4 w = wg4[d*4 + j];
          lg[4*j+0] += xc*w.x; lg[4*j+1] += xc*w.y;
          lg[4*j+2] += xc*w.z; lg[4*j+3] += xc*w.w;
        }
      }
    }
#pragma unroll
    for (int e = 0; e < 16; ++e) sm.g.lgp[kc][tk][e] = lg[e];
    __syncthreads();
    if (tid < 64) {
      int lane = tid;
      float l[16];
#pragma unroll
      for (int e = 0; e < 16; ++e)
        l[e] = sm.g.lgp[0][lane][e] + sm.g.lgp[1][lane][e]
             + sm.g.lgp[2][lane][e] + sm.g.lgp[3][lane][e];
      float mx = l[0];
#pragma unroll
      for (int e = 1; e < 16; ++e) mx = fmaxf(mx, l[e]);
      float p[16]; float s = 0.f;
#pragma unroll
      for (int e = 0; e < 16; ++e) { p[e] = expf(l[e] - mx); s += p[e]; }
      int i1 = 0; float b1 = p[0];
#pragma unroll
      for (int e = 1; e < 16; ++e) { if (p[e] > b1) { b1 = p[e]; i1 = e; } }
      float b2 = (i1 == 0) ? 0.f : p[0]; int i2 = 0;
#pragma unroll
      for (int e = 1; e < 16; ++e) { float v = (e == i1) ? 0.f : p[e]; if (v > b2) { b2 = v; i2 = e; } }
      float inv = 1.f / s;
      float g1 = b1*inv, g2 = b2*inv;
      float den = g1 + g2 + 1e-9f;
      g1 /= den; g2 /= den;
      int tok = token0 + lane;
      idx1a[tok] = i1; idx2a[tok] = i2;
      g1a[tok] = g1;   g2a[tok] = g2;
      int blk = blockIdx.x;   // 32 blocks per batch, blk = b*32 + chunk
#pragma unroll
      for (int e = 0; e < 16; ++e) {
        float v = p[e] * inv;
        v += __shfl_down(v, 32); v += __shfl_down(v, 16);
        v += __shfl_down(v, 8);  v += __shfl_down(v, 4);
        v += __shfl_down(v, 2);  v += __shfl_down(v, 1);
        unsigned long long mb = __ballot(i1 == e);
        if (lane == 0) {
          raw_part[blk*16 + e] = v;
          cnt_part[blk*16 + e] = (float)__popcll(mb);
        }
      }
    }
  } else {
    // ---------------- qr per (e,h) ----------------
    int eh = blockIdx.x - 256;
    int e = eh >> 3, h = eh & 7;
    for (int i = tid; i < 2048; i += 256) { int b = i >> 8, k = i & 255; sm.q.aS[k][b] = audio[b*DD + k]; }
    __syncthreads();
    int j = tid & 31, kg = tid >> 5;
    const float* wq = Wq + (size_t)e*DD*DD + h*32 + j;
    float acc[8] = {0,0,0,0,0,0,0,0};
#pragma unroll
    for (int i = 0; i < 32; ++i) {
      int k = kg*32 + i;
      float w = wq[(size_t)k*DD];
      float4 a0 = *(const float4*)&sm.q.aS[k][0];
      float4 a1 = *(const float4*)&sm.q.aS[k][4];
      acc[0]+=w*a0.x; acc[1]+=w*a0.y; acc[2]+=w*a0.z; acc[3]+=w*a0.w;
      acc[4]+=w*a1.x; acc[5]+=w*a1.y; acc[6]+=w*a1.z; acc[7]+=w*a1.w;
    }
#pragma unroll
    for (int b = 0; b < 8; ++b) sm.q.qpart[kg][j][b] = acc[b];
    const float* wkbase = Wkv + (size_t)e*(DD*2*DD) + h*32;
    float4 stg[8];
#pragma unroll
    for (int m = 0; m < 8; ++m) {
      int row = m*32 + (tid >> 3), c4 = tid & 7;
      stg[m] = *(const float4*)(wkbase + (size_t)row*(2*DD) + c4*4);
    }
#pragma unroll
    for (int m = 0; m < 8; ++m) {
      int row = m*32 + (tid >> 3), c4 = tid & 7;
      sm.q.wkS[row][c4*4+0] = stg[m].x; sm.q.wkS[row][c4*4+1] = stg[m].y;
      sm.q.wkS[row][c4*4+2] = stg[m].z; sm.q.wkS[row][c4*4+3] = stg[m].w;
    }
    __syncthreads();
    {
      int jj = tid >> 3, b = tid & 7;
      float s = 0.f;
#pragma unroll
      for (int g = 0; g < 8; ++g) s += sm.q.qpart[g][jj][b];
      sm.q.qS[jj][b] = s;
    }
    __syncthreads();
    int d = tid;
    float racc[8] = {0,0,0,0,0,0,0,0};
#pragma unroll
    for (int jj = 0; jj < 32; ++jj) {
      float w = sm.q.wkS[d][jj];
      float4 q0 = *(const float4*)&sm.q.qS[jj][0];
      float4 q1 = *(const float4*)&sm.q.qS[jj][4];
      racc[0]+=w*q0.x; racc[1]+=w*q0.y; racc[2]+=w*q0.z; racc[3]+=w*q0.w;
      racc[4]+=w*q1.x; racc[5]+=w*q1.y; racc[6]+=w*q1.z; racc[7]+=w*q1.w;
    }
#pragma unroll
    for (int b = 0; b < 8; ++b)
      rws[((size_t)(e*8 + b))*2048 + d*8 + h] = racc[b];
  }
}

// ================================================================ kernel 2: scan (per batch) + slot init + loss
__global__ __launch_bounds__(256) void scan_kernel(
    const int* __restrict__ idx1a, const int* __restrict__ idx2a,
    float* __restrict__ g1a, float* __restrict__ g2a, int* __restrict__ slot_token,
    const float* __restrict__ raw_part, const float* __restrict__ cnt_part,
    float* __restrict__ out_loss)
{
  __shared__ unsigned long long m1s[16][32], m2s[16][32];
  __shared__ int wp1[16][32], wp2[16][32], mcnt[16];
  int b = blockIdx.x, tid = threadIdx.x;
  int wave = tid >> 6, lane = tid & 63;
  // init slot_token rows owned by this block (rows (e*BB+b), all e)
  for (int i = tid; i < 16*CAPC; i += 256) {
    int e = i >> 8, s = i & 255;
    slot_token[(e*BB + b)*CAPC + s] = -1;
  }
  for (int w = wave; w < 32; w += 4) {
    int token = b*NN + w*64 + lane;
    int i1 = idx1a[token], i2 = idx2a[token];
#pragma unroll
    for (int e = 0; e < 16; ++e) {
      unsigned long long ma = __ballot(i1 == e);
      unsigned long long mb = __ballot(i2 == e);
      if (lane == 0) { m1s[e][w] = ma; m2s[e][w] = mb; }
    }
  }
  __syncthreads();
  if (tid < 16) {
    int run = 0;
    for (int w = 0; w < 32; ++w) { wp1[tid][w] = run; run += (int)__popcll(m1s[tid][w]); }
    mcnt[tid] = run < CAPC ? run : CAPC;
  } else if (tid < 32) {
    int e2 = tid - 16; int run = 0;
    for (int w = 0; w < 32; ++w) { wp2[e2][w] = run; run += (int)__popcll(m2s[e2][w]); }
  }
  __syncthreads();
  for (int w = wave; w < 32; w += 4) {
    int token = b*NN + w*64 + lane;
    int i1 = idx1a[token], i2 = idx2a[token];
    unsigned long long lt = (1ull << lane) - 1ull;
    int pos1 = wp1[i1][w] + (int)__popcll(m1s[i1][w] & lt);
    float g1 = g1a[token];
    bool k1 = pos1 < CAPC;
    g1a[token] = k1 ? g1 : 0.f;
    if (k1) slot_token[(i1*BB + b)*CAPC + pos1] = token;
    int pos2 = mcnt[i2] + wp2[i2][w] + (int)__popcll(m2s[i2][w] & lt);
    float g2 = g2a[token];
    bool k2 = pos2 < CAPC;
    g2a[token] = k2 ? g2 : 0.f;
    if (k2 && g2 > 0.f) slot_token[(i2*BB + b)*CAPC + pos2] = token;
  }
  // ---- loss from per-block partials (complete: previous launch)
  if (blockIdx.x == 0) {
    float v = 0.f;
    if (tid < 128) {
      int bb = tid >> 4, e = tid & 15;
      float rs = 0.f, cs = 0.f;
#pragma unroll 4
      for (int k = 0; k < 32; ++k) {
        rs += raw_part[(bb*32 + k)*16 + e];
        cs += cnt_part[(bb*32 + k)*16 + e];
      }
      v = (rs * (1.f/(float)NN)) * (cs * (1.f/(float)NN));
    }
    v += __shfl_down(v, 32); v += __shfl_down(v, 16); v += __shfl_down(v, 8);
    v += __shfl_down(v, 4);  v += __shfl_down(v, 2);  v += __shfl_down(v, 1);
    __shared__ float r4[4];
    if ((tid & 63) == 0) r4[tid >> 6] = v;
    __syncthreads();
    if (tid == 0)
      out_loss[0] = (r4[0]+r4[1]+r4[2]+r4[3]) * ((float)(EE*EE) / (float)(BB*EE)) * 0.01f;
  }
}

// ================================================================ kernel 3: mixer per (e,b)
// logits -> softmax -> xattn=attn@Xslot (LDS) -> o=xattn@Wv -> gate=sigmoid(o@Wp+bp)
__global__ __launch_bounds__(256) void mixer_kernel(
    const float* __restrict__ x, const float* __restrict__ rws,
    const float* __restrict__ Wkv, const float* __restrict__ Wp,
    const float* __restrict__ bp, const int* __restrict__ slot_token,
    float* __restrict__ gateW)
{
  __shared__ int tokS[CAPC];
  __shared__ float red[16];
  __shared__ float aS[CAPC][9];          // logits / exp / attn (9 KB, pad 9)
  __shared__ union {
    float rS[DD][8];                     // phase A   (8 KB)
    float xa[HH][DD];                    // post-reduce (8 KB)
  } u1;
  __shared__ float4 part[4][HH][64];     // 32 KB
  __shared__ float oS[DD];
  int tid = threadIdx.x, eb = blockIdx.x, e = eb >> 3;
  // stage r and tokens
  {
    const float4* rin = (const float4*)(rws + (size_t)eb*2048);
    float4* rS4 = (float4*)u1.rS;
    rS4[tid] = rin[tid]; rS4[tid+256] = rin[tid+256];
    tokS[tid] = slot_token[eb*CAPC + tid];
  }
  __syncthreads();
  // ---- phase A: per-slot logits (thread = slot)
  int token = tokS[tid];
  float l[8] = {0,0,0,0,0,0,0,0};
  if (token >= 0) {
    const float4* xr = (const float4*)(x + (size_t)token*DD);
#pragma unroll 8
    for (int d4 = 0; d4 < 64; ++d4) {
      float4 xv = xr[d4];
      float xa4[4] = {xv.x, xv.y, xv.z, xv.w};
#pragma unroll
      for (int dd = 0; dd < 4; ++dd) {
        int d = d4*4 + dd;
        float4 r0 = *(const float4*)&u1.rS[d][0];
        float4 r1 = *(const float4*)&u1.rS[d][4];
        float xc = xa4[dd];
        l[0]+=xc*r0.x; l[1]+=xc*r0.y; l[2]+=xc*r0.z; l[3]+=xc*r0.w;
        l[4]+=xc*r1.x; l[5]+=xc*r1.y; l[6]+=xc*r1.z; l[7]+=xc*r1.w;
      }
    }
#pragma unroll
    for (int h = 0; h < 8; ++h) l[h] *= 0.17677669529663687f;  // 32^-0.5
  }
#pragma unroll
  for (int h = 0; h < 8; ++h) aS[tid][h] = l[h];
  __syncthreads();
  // ---- softmax over 256 slots per head
  int lane = tid & 63, wave = tid >> 6;
#pragma unroll
  for (int r = 0; r < 2; ++r) {
    int hh = wave + r*4;
    float m = fmaxf(fmaxf(aS[lane][hh], aS[lane+64][hh]),
                    fmaxf(aS[lane+128][hh], aS[lane+192][hh]));
    m = fmaxf(m, __shfl_down(m,32)); m = fmaxf(m, __shfl_down(m,16));
    m = fmaxf(m, __shfl_down(m,8));  m = fmaxf(m, __shfl_down(m,4));
    m = fmaxf(m, __shfl_down(m,2));  m = fmaxf(m, __shfl_down(m,1));
    if (lane == 0) red[hh] = m;
  }
  __syncthreads();
  float ex[8];
#pragma unroll
  for (int h = 0; h < 8; ++h) { ex[h] = expf(l[h] - red[h]); aS[tid][h] = ex[h]; }
  __syncthreads();
#pragma unroll
  for (int r = 0; r < 2; ++r) {
    int hh = wave + r*4;
    float s = aS[lane][hh] + aS[lane+64][hh] + aS[lane+128][hh] + aS[lane+192][hh];
    s += __shfl_down(s,32); s += __shfl_down(s,16); s += __shfl_down(s,8);
    s += __shfl_down(s,4);  s += __shfl_down(s,2);  s += __shfl_down(s,1);
    if (lane == 0) red[8+hh] = s;
  }
  __syncthreads();
#pragma unroll
  for (int h = 0; h < 8; ++h) aS[tid][h] = ex[h] / red[8+h];
  __syncthreads();
  // ---- phase B: xattn[h][d] = sum_s attn[h][s]*x[tok_s][d]; thread=(c4,sc), float4-coalesced
  int c4 = tid & 63, sc = tid >> 6;
  float4 acc[8];
#pragma unroll
  for (int h = 0; h < 8; ++h) acc[h] = make_float4(0.f,0.f,0.f,0.f);
  const float4* x4 = (const float4*)x;
#pragma unroll 4
  for (int i = 0; i < 64; ++i) {
    int s = sc*64 + i;
    int tk = tokS[s];
    int tkc = tk < 0 ? 0 : tk;
    float msk = tk < 0 ? 0.f : 1.f;
    float4 xv = x4[(size_t)tkc*64 + c4];
    xv.x *= msk; xv.y *= msk; xv.z *= msk; xv.w *= msk;
#pragma unroll
    for (int h = 0; h < 8; ++h) {
      float a = aS[s][h];
      acc[h].x += a*xv.x; acc[h].y += a*xv.y; acc[h].z += a*xv.z; acc[h].w += a*xv.w;
    }
  }
#pragma unroll
  for (int h = 0; h < 8; ++h) part[sc][h][c4] = acc[h];
  __syncthreads();
  // reduce 4 partials -> u1.xa  (512 float4 outputs, 2 per thread)
#pragma unroll
  for (int r = 0; r < 2; ++r) {
    int o = tid*2 + r;
    int h = o >> 6, cc = o & 63;
    float4 s0 = part[0][h][cc], s1 = part[1][h][cc], s2 = part[2][h][cc], s3 = part[3][h][cc];
    float4 s;
    s.x = s0.x+s1.x+s2.x+s3.x; s.y = s0.y+s1.y+s2.y+s3.y;
    s.z = s0.z+s1.z+s2.z+s3.z; s.w = s0.w+s1.w+s2.w+s3.w;
    ((float4*)&u1.xa[h][0])[cc] = s;
  }
  __syncthreads();
  // ---- o[c] = sum_d xa[c>>5][d] * Wv[e][d][256+c]
  {
    int c = tid, h = c >> 5;
    const float* wv = Wkv + (size_t)e*(DD*2*DD) + DD + c;
    float acc2 = 0.f;
#pragma unroll 8
    for (int d = 0; d < DD; ++d) acc2 += u1.xa[h][d] * wv[(size_t)d*(2*DD)];
    oS[c] = acc2;
  }
  __syncthreads();
  // ---- gate[c] = sigmoid(bp[c] + sum_j o[j]*Wp[e][j][c])
  {
    int c = tid;
    const float* wp = Wp + (size_t)e*DD*DD + c;
    float s = bp[e*DD + c];
#pragma unroll 8
    for (int jj = 0; jj < DD; ++jj) s += oS[jj] * wp[(size_t)jj*DD];
    gateW[(size_t)eb*DD + c] = 1.f / (1.f + expf(-s));
  }
}

// ================================================================ kernel 4: recombine (float4)
__global__ __launch_bounds__(256) void out_kernel(
    const float* __restrict__ x, const float* __restrict__ g1f, const float* __restrict__ g2f,
    const int* __restrict__ idx1a, const int* __restrict__ idx2a,
    const float* __restrict__ gateW, float* __restrict__ out)
{
  int idx = blockIdx.x*256 + threadIdx.x;   // float4 index
  int token = idx >> 6;
  int d4 = idx & 63;
  int b = token >> 11;
  float g1 = g1f[token], g2 = g2f[token];
  int e1 = idx1a[token], e2 = idx2a[token];
  float4 w1 = ((const float4*)(gateW + (size_t)(e1*BB+b)*DD))[d4];
  float4 w2 = ((const float4*)(gateW + (size_t)(e2*BB+b)*DD))[d4];
  float4 xv = ((const float4*)x)[idx];
  float4 o;
  o.x = xv.x*(g1*w1.x + g2*w2.x);
  o.y = xv.y*(g1*w1.y + g2*w2.y);
  o.z = xv.z*(g1*w1.z + g2*w2.z);
  o.w = xv.w*(g1*w1.w + g2*w2.w);
  ((float4*)out)[idx] = o;
}

// ================================================================ launcher
extern "C" void kernel_launch(void* const* d_in, const int* in_sizes, int n_in,
                              void* d_out, int out_size, void* d_ws, size_t ws_size,
                              hipStream_t stream)
{
  const float* x     = (const float*)d_in[0];
  const float* audio = (const float*)d_in[1];
  const float* wg    = (const float*)d_in[2];
  const float* Wq    = (const float*)d_in[3];
  const float* Wkv   = (const float*)d_in[4];
  const float* Wp    = (const float*)d_in[5];
  const float* bp    = (const float*)d_in[6];
  float* out = (float*)d_out;

  // workspace (~1.8 MB), no memsets needed
  float* raw_part = (float*)d_ws;                      // 256*16
  float* cnt_part = raw_part + 256*16;                 // 256*16
  int*   idx1a   = (int*)(cnt_part + 256*16);          // BN
  int*   idx2a   = idx1a + BN;                         // BN
  float* g1a     = (float*)(idx2a + BN);               // BN (scan truncates in place)
  float* g2a     = g1a + BN;                           // BN
  int*   slot_token = (int*)(g2a + BN);                // EB*CAP = 32768
  float* rws     = (float*)(slot_token + EB*CAPC);     // EB*2048 = 262144
  float* gateW   = rws + (size_t)EB*2048;              // EB*256 = 32768

  fused_gq_kernel<<<384, 256, 0, stream>>>(x, wg, audio, Wq, Wkv,
                                           idx1a, idx2a, g1a, g2a,
                                           raw_part, cnt_part, rws);
  scan_kernel<<<BB, 256, 0, stream>>>(idx1a, idx2a, g1a, g2a, slot_token,
                                      raw_part, cnt_part, out + (size_t)out_size - 1);
  mixer_kernel<<<EB, 256, 0, stream>>>(x, rws, Wkv, Wp, bp, slot_token, gateW);
  out_kernel<<<(BN*DD/4)/256, 256, 0, stream>>>(x, g1a, g2a, idx1a, idx2a, gateW, out);
}

// Round 5
// 152.146 us; speedup vs baseline: 2.4451x; 1.0685x over previous
//
#include <hip/hip_runtime.h>
#include <cstdint>
#include <cstddef>

#define BB 8
#define NN 2048
#define DD 256
#define EE 16
#define HH 8
#define CAPC 256
#define BN (BB*NN)   // 16384
#define EB (EE*BB)   // 128

// ================================================================ kernel 1:
// blocks 0..255   : gating (64 tokens each), per-block loss partials (no atomics)
// blocks 256..383 : qr per (e,h): q[b]=audio[b]@Wq[e]; r[b][d]=Wk[e][d,h*32:]·q_head
__global__ __launch_bounds__(256) void fused_gq_kernel(
    const float* __restrict__ x, const float* __restrict__ wg,
    const float* __restrict__ audio, const float* __restrict__ Wq,
    const float* __restrict__ Wkv,
    int* __restrict__ idx1a, int* __restrict__ idx2a,
    float* __restrict__ g1a, float* __restrict__ g2a,
    float* __restrict__ raw_part, float* __restrict__ cnt_part,
    float* __restrict__ rws)
{
  __shared__ union SM {
    struct { float wgS[DD*EE]; float lgp[4][64][17]; } g;                     // 33.4 KB
    struct { float aS[DD][8]; float qpart[8][32][9]; float qS[32][8];
             float wkS[DD][33]; } q;                                          // 52 KB
  } sm;
  int tid = threadIdx.x;

  if (blockIdx.x < 256) {
    // ---------------- gating ----------------
    for (int t = tid; t < DD*EE; t += 256) sm.g.wgS[t] = wg[t];
    __syncthreads();
    int tk = tid & 63, kc = tid >> 6;
    int token0 = blockIdx.x * 64;
    int token = token0 + tk;
    const float4* xr = (const float4*)(x + (size_t)token*DD + kc*64);
    const float4* wg4 = (const float4*)sm.g.wgS;
    float lg[16];
#pragma unroll
    for (int e = 0; e < 16; ++e) lg[e] = 0.f;
#pragma unroll
    for (int d4 = 0; d4 < 16; ++d4) {
      float4 xv = xr[d4];
      float xa[4] = {xv.x, xv.y, xv.z, xv.w};
#pragma unroll
      for (int dd = 0; dd < 4; ++dd) {
        int d = kc*64 + d4*4 + dd;
        float xc = xa[dd];
#pragma unroll
        for (int j = 0; j < 4; ++j) {
          float4 w = wg4[d*4 + j];
          lg[4*j+0] += xc*w.x; lg[4*j+1] += xc*w.y;
          lg[4*j+2] += xc*w.z; lg[4*j+3] += xc*w.w;
        }
      }
    }
#pragma unroll
    for (int e = 0; e < 16; ++e) sm.g.lgp[kc][tk][e] = lg[e];
    __syncthreads();
    if (tid < 64) {
      int lane = tid;
      float l[16];
#pragma unroll
      for (int e = 0; e < 16; ++e)
        l[e] = sm.g.lgp[0][lane][e] + sm.g.lgp[1][lane][e]
             + sm.g.lgp[2][lane][e] + sm.g.lgp[3][lane][e];
      float mx = l[0];
#pragma unroll
      for (int e = 1; e < 16; ++e) mx = fmaxf(mx, l[e]);
      float p[16]; float s = 0.f;
#pragma unroll
      for (int e = 0; e < 16; ++e) { p[e] = expf(l[e] - mx); s += p[e]; }
      int i1 = 0; float b1 = p[0];
#pragma unroll
      for (int e = 1; e < 16; ++e) { if (p[e] > b1) { b1 = p[e]; i1 = e; } }
      float b2 = (i1 == 0) ? 0.f : p[0]; int i2 = 0;
#pragma unroll
      for (int e = 1; e < 16; ++e) { float v = (e == i1) ? 0.f : p[e]; if (v > b2) { b2 = v; i2 = e; } }
      float inv = 1.f / s;
      float g1 = b1*inv, g2 = b2*inv;
      float den = g1 + g2 + 1e-9f;
      g1 /= den; g2 /= den;
      int tok = token0 + lane;
      idx1a[tok] = i1; idx2a[tok] = i2;
      g1a[tok] = g1;   g2a[tok] = g2;
      int blk = blockIdx.x;
#pragma unroll
      for (int e = 0; e < 16; ++e) {
        float v = p[e] * inv;
        v += __shfl_down(v, 32); v += __shfl_down(v, 16);
        v += __shfl_down(v, 8);  v += __shfl_down(v, 4);
        v += __shfl_down(v, 2);  v += __shfl_down(v, 1);
        unsigned long long mb = __ballot(i1 == e);
        if (lane == 0) {
          raw_part[blk*16 + e] = v;
          cnt_part[blk*16 + e] = (float)__popcll(mb);
        }
      }
    }
  } else {
    // ---------------- qr per (e,h) ----------------
    int eh = blockIdx.x - 256;
    int e = eh >> 3, h = eh & 7;
    for (int i = tid; i < 2048; i += 256) { int b = i >> 8, k = i & 255; sm.q.aS[k][b] = audio[b*DD + k]; }
    __syncthreads();
    int j = tid & 31, kg = tid >> 5;
    const float* wq = Wq + (size_t)e*DD*DD + h*32 + j;
    float acc[8] = {0,0,0,0,0,0,0,0};
#pragma unroll
    for (int i = 0; i < 32; ++i) {
      int k = kg*32 + i;
      float w = wq[(size_t)k*DD];
      float4 a0 = *(const float4*)&sm.q.aS[k][0];
      float4 a1 = *(const float4*)&sm.q.aS[k][4];
      acc[0]+=w*a0.x; acc[1]+=w*a0.y; acc[2]+=w*a0.z; acc[3]+=w*a0.w;
      acc[4]+=w*a1.x; acc[5]+=w*a1.y; acc[6]+=w*a1.z; acc[7]+=w*a1.w;
    }
#pragma unroll
    for (int b = 0; b < 8; ++b) sm.q.qpart[kg][j][b] = acc[b];
    const float* wkbase = Wkv + (size_t)e*(DD*2*DD) + h*32;
    float4 stg[8];
#pragma unroll
    for (int m = 0; m < 8; ++m) {
      int row = m*32 + (tid >> 3), c4 = tid & 7;
      stg[m] = *(const float4*)(wkbase + (size_t)row*(2*DD) + c4*4);
    }
#pragma unroll
    for (int m = 0; m < 8; ++m) {
      int row = m*32 + (tid >> 3), c4 = tid & 7;
      sm.q.wkS[row][c4*4+0] = stg[m].x; sm.q.wkS[row][c4*4+1] = stg[m].y;
      sm.q.wkS[row][c4*4+2] = stg[m].z; sm.q.wkS[row][c4*4+3] = stg[m].w;
    }
    __syncthreads();
    {
      int jj = tid >> 3, b = tid & 7;
      float s = 0.f;
#pragma unroll
      for (int g = 0; g < 8; ++g) s += sm.q.qpart[g][jj][b];
      sm.q.qS[jj][b] = s;
    }
    __syncthreads();
    int d = tid;
    float racc[8] = {0,0,0,0,0,0,0,0};
#pragma unroll
    for (int jj = 0; jj < 32; ++jj) {
      float w = sm.q.wkS[d][jj];
      float4 q0 = *(const float4*)&sm.q.qS[jj][0];
      float4 q1 = *(const float4*)&sm.q.qS[jj][4];
      racc[0]+=w*q0.x; racc[1]+=w*q0.y; racc[2]+=w*q0.z; racc[3]+=w*q0.w;
      racc[4]+=w*q1.x; racc[5]+=w*q1.y; racc[6]+=w*q1.z; racc[7]+=w*q1.w;
    }
#pragma unroll
    for (int b = 0; b < 8; ++b)
      rws[((size_t)(e*8 + b))*2048 + d*8 + h] = racc[b];
  }
}

// ================================================================ kernel 2: scan (per batch) + slot init + loss
__global__ __launch_bounds__(256) void scan_kernel(
    const int* __restrict__ idx1a, const int* __restrict__ idx2a,
    float* __restrict__ g1a, float* __restrict__ g2a, int* __restrict__ slot_token,
    const float* __restrict__ raw_part, const float* __restrict__ cnt_part,
    float* __restrict__ out_loss)
{
  __shared__ unsigned long long m1s[16][32], m2s[16][32];
  __shared__ int wp1[16][32], wp2[16][32], mcnt[16];
  int b = blockIdx.x, tid = threadIdx.x;
  int wave = tid >> 6, lane = tid & 63;
  for (int i = tid; i < 16*CAPC; i += 256) {
    int e = i >> 8, s = i & 255;
    slot_token[(e*BB + b)*CAPC + s] = -1;
  }
  for (int w = wave; w < 32; w += 4) {
    int token = b*NN + w*64 + lane;
    int i1 = idx1a[token], i2 = idx2a[token];
#pragma unroll
    for (int e = 0; e < 16; ++e) {
      unsigned long long ma = __ballot(i1 == e);
      unsigned long long mb = __ballot(i2 == e);
      if (lane == 0) { m1s[e][w] = ma; m2s[e][w] = mb; }
    }
  }
  __syncthreads();
  if (tid < 16) {
    int run = 0;
    for (int w = 0; w < 32; ++w) { wp1[tid][w] = run; run += (int)__popcll(m1s[tid][w]); }
    mcnt[tid] = run < CAPC ? run : CAPC;
  } else if (tid < 32) {
    int e2 = tid - 16; int run = 0;
    for (int w = 0; w < 32; ++w) { wp2[e2][w] = run; run += (int)__popcll(m2s[e2][w]); }
  }
  __syncthreads();
  for (int w = wave; w < 32; w += 4) {
    int token = b*NN + w*64 + lane;
    int i1 = idx1a[token], i2 = idx2a[token];
    unsigned long long lt = (1ull << lane) - 1ull;
    int pos1 = wp1[i1][w] + (int)__popcll(m1s[i1][w] & lt);
    float g1 = g1a[token];
    bool k1 = pos1 < CAPC;
    g1a[token] = k1 ? g1 : 0.f;
    if (k1) slot_token[(i1*BB + b)*CAPC + pos1] = token;
    int pos2 = mcnt[i2] + wp2[i2][w] + (int)__popcll(m2s[i2][w] & lt);
    float g2 = g2a[token];
    bool k2 = pos2 < CAPC;
    g2a[token] = k2 ? g2 : 0.f;
    if (k2 && g2 > 0.f) slot_token[(i2*BB + b)*CAPC + pos2] = token;
  }
  if (blockIdx.x == 0) {
    float v = 0.f;
    if (tid < 128) {
      int bb = tid >> 4, e = tid & 15;
      float rs = 0.f, cs = 0.f;
#pragma unroll 4
      for (int k = 0; k < 32; ++k) {
        rs += raw_part[(bb*32 + k)*16 + e];
        cs += cnt_part[(bb*32 + k)*16 + e];
      }
      v = (rs * (1.f/(float)NN)) * (cs * (1.f/(float)NN));
    }
    v += __shfl_down(v, 32); v += __shfl_down(v, 16); v += __shfl_down(v, 8);
    v += __shfl_down(v, 4);  v += __shfl_down(v, 2);  v += __shfl_down(v, 1);
    __shared__ float r4[4];
    if ((tid & 63) == 0) r4[tid >> 6] = v;
    __syncthreads();
    if (tid == 0)
      out_loss[0] = (r4[0]+r4[1]+r4[2]+r4[3]) * ((float)(EE*EE) / (float)(BB*EE)) * 0.01f;
  }
}

// ================================================================ kernel 3: per-slot logits, grid = eb*4 (64 slots each)
__global__ __launch_bounds__(256) void lslotB_kernel(
    const float* __restrict__ x, const float* __restrict__ rws,
    const int* __restrict__ slot_token, float* __restrict__ lslot)
{
  __shared__ float rS[DD][8];      // 8 KB  [d][h]
  __shared__ float lp[4][64][9];   // 9.2 KB partials (pad 9)
  __shared__ int tokS[64];
  int tid = threadIdx.x;
  int eb = blockIdx.x >> 2, sc = blockIdx.x & 3;
  {
    const float4* rin = (const float4*)(rws + (size_t)eb*2048);
    float4* rS4 = (float4*)rS;
    rS4[tid] = rin[tid]; rS4[tid+256] = rin[tid+256];
  }
  if (tid < 64) tokS[tid] = slot_token[eb*CAPC + sc*64 + tid];
  __syncthreads();
  int s = tid >> 2, q = tid & 3;
  int token = tokS[s];
  float l[8] = {0,0,0,0,0,0,0,0};
  if (token >= 0) {
    const float4* xr = (const float4*)(x + (size_t)token*DD + q*64);
#pragma unroll
    for (int i = 0; i < 16; ++i) {
      float4 xv = xr[i];
      float xa[4] = {xv.x, xv.y, xv.z, xv.w};
#pragma unroll
      for (int dd = 0; dd < 4; ++dd) {
        int d = q*64 + i*4 + dd;
        float4 r0 = *(const float4*)&rS[d][0];
        float4 r1 = *(const float4*)&rS[d][4];
        float xc = xa[dd];
        l[0]+=xc*r0.x; l[1]+=xc*r0.y; l[2]+=xc*r0.z; l[3]+=xc*r0.w;
        l[4]+=xc*r1.x; l[5]+=xc*r1.y; l[6]+=xc*r1.z; l[7]+=xc*r1.w;
      }
    }
  }
#pragma unroll
  for (int h = 0; h < 8; ++h) lp[q][s][h] = l[h];
  __syncthreads();
#pragma unroll
  for (int r = 0; r < 2; ++r) {
    int o = tid*2 + r;               // 0..511
    int ss = o >> 3, h = o & 7;
    float v = (lp[0][ss][h] + lp[1][ss][h] + lp[2][ss][h] + lp[3][ss][h])
            * 0.17677669529663687f;  // 32^-0.5
    lslot[((size_t)eb*CAPC + sc*64 + ss)*8 + h] = v;
  }
}

// ================================================================ kernel 4: softmax + xattn chunk, grid = eb*4 (64 d each)
__global__ __launch_bounds__(256) void xattn_kernel(
    const float* __restrict__ x, const float* __restrict__ lslot,
    const int* __restrict__ slot_token, float* __restrict__ xattn)
{
  __shared__ float lS[CAPC][9];      // 9 KB
  __shared__ float aS[HH][CAPC];     // 8 KB
  __shared__ float part[4][HH][64];  // 8 KB
  __shared__ int tokS[CAPC];
  __shared__ float red[16];
  int tid = threadIdx.x;
  int eb = blockIdx.x >> 2, dc = blockIdx.x & 3;
  int d0 = dc*64;
  {
    const float4* li = (const float4*)(lslot + (size_t)eb*CAPC*8);
    float4 v0 = li[tid*2], v1 = li[tid*2+1];
    lS[tid][0]=v0.x; lS[tid][1]=v0.y; lS[tid][2]=v0.z; lS[tid][3]=v0.w;
    lS[tid][4]=v1.x; lS[tid][5]=v1.y; lS[tid][6]=v1.z; lS[tid][7]=v1.w;
    tokS[tid] = slot_token[eb*CAPC + tid];
  }
  __syncthreads();
  int lane = tid & 63, wave = tid >> 6;
#pragma unroll
  for (int r = 0; r < 2; ++r) {
    int hh = wave + r*4;
    float m = fmaxf(fmaxf(lS[lane][hh], lS[lane+64][hh]),
                    fmaxf(lS[lane+128][hh], lS[lane+192][hh]));
    m = fmaxf(m, __shfl_down(m,32)); m = fmaxf(m, __shfl_down(m,16));
    m = fmaxf(m, __shfl_down(m,8));  m = fmaxf(m, __shfl_down(m,4));
    m = fmaxf(m, __shfl_down(m,2));  m = fmaxf(m, __shfl_down(m,1));
    if (lane == 0) red[hh] = m;
  }
  __syncthreads();
  float ex[8];
#pragma unroll
  for (int h = 0; h < 8; ++h) { ex[h] = expf(lS[tid][h] - red[h]); lS[tid][h] = ex[h]; }
  __syncthreads();
#pragma unroll
  for (int r = 0; r < 2; ++r) {
    int hh = wave + r*4;
    float s = lS[lane][hh] + lS[lane+64][hh] + lS[lane+128][hh] + lS[lane+192][hh];
    s += __shfl_down(s,32); s += __shfl_down(s,16); s += __shfl_down(s,8);
    s += __shfl_down(s,4);  s += __shfl_down(s,2);  s += __shfl_down(s,1);
    if (lane == 0) red[8+hh] = s;
  }
  __syncthreads();
#pragma unroll
  for (int h = 0; h < 8; ++h) aS[h][tid] = ex[h] / red[8+h];
  __syncthreads();
  // gather: thread (d in 64, sc in 4), 64 slots each; coalesced 256B rows
  int d = tid & 63, sc = tid >> 6;
  const float* xb = x + d0 + d;
  float acc[8] = {0,0,0,0,0,0,0,0};
#pragma unroll 4
  for (int i = 0; i < 64; ++i) {
    int s = sc*64 + i;
    int tk = tokS[s];
    int tkc = tk < 0 ? 0 : tk;
    float msk = tk < 0 ? 0.f : 1.f;
    float xv = xb[(size_t)tkc*DD] * msk;
#pragma unroll
    for (int h = 0; h < 8; ++h) acc[h] += aS[h][s] * xv;
  }
#pragma unroll
  for (int h = 0; h < 8; ++h) part[sc][h][d] = acc[h];
  __syncthreads();
#pragma unroll
  for (int r = 0; r < 2; ++r) {
    int o = r*256 + tid;
    int h = o >> 6, d2 = o & 63;
    float v = part[0][h][d2] + part[1][h][d2] + part[2][h][d2] + part[3][h][d2];
    xattn[(size_t)eb*2048 + h*DD + d0 + d2] = v;
  }
}

// ================================================================ kernel 5: o = xattn @ Wv  per (e, head-chunk)
__global__ __launch_bounds__(256) void o_kernel(
    const float* __restrict__ xattn, const float* __restrict__ Wkv,
    float* __restrict__ o_ws)
{
  __shared__ float xaS[8][DD];       // 8 KB [b][d] for this h
  __shared__ float op[8][32][9];     // 9.2 KB
  int tid = threadIdx.x;
  int e = blockIdx.x >> 3, ch = blockIdx.x & 7;
  int c0 = ch*32, h = ch;
  for (int i = tid; i < 2048; i += 256) {
    int b = i >> 8, d = i & 255;
    xaS[b][d] = xattn[((size_t)(e*8 + b))*2048 + h*DD + d];
  }
  __syncthreads();
  int c = tid & 31, kc = tid >> 5;
  const float* wv = Wkv + (size_t)e*(DD*2*DD) + DD + c0 + c;
  float acc[8] = {0,0,0,0,0,0,0,0};
#pragma unroll
  for (int i = 0; i < 32; ++i) {
    int d = kc*32 + i;
    float w = wv[(size_t)d*(2*DD)];
#pragma unroll
    for (int b = 0; b < 8; ++b) acc[b] += w * xaS[b][d];
  }
#pragma unroll
  for (int b = 0; b < 8; ++b) op[kc][c][b] = acc[b];
  __syncthreads();
  int c2 = tid & 31, b2 = tid >> 5;
  float s = 0.f;
#pragma unroll
  for (int g = 0; g < 8; ++g) s += op[g][c2][b2];
  o_ws[((size_t)(e*8 + b2))*DD + c0 + c2] = s;
}

// ================================================================ kernel 6: gate = sigmoid(o @ Wp + bp)  per (e, col-chunk)
__global__ __launch_bounds__(256) void gate_kernel(
    const float* __restrict__ o_ws, const float* __restrict__ Wp,
    const float* __restrict__ bp, float* __restrict__ gateW)
{
  __shared__ float oS[8][DD];        // 8 KB
  __shared__ float op[8][32][9];
  int tid = threadIdx.x;
  int e = blockIdx.x >> 3, ch = blockIdx.x & 7;
  int c0 = ch*32;
  for (int i = tid; i < 2048; i += 256) {
    int b = i >> 8, d = i & 255;
    oS[b][d] = o_ws[((size_t)(e*8 + b))*DD + d];
  }
  __syncthreads();
  int c = tid & 31, kc = tid >> 5;
  const float* wp = Wp + (size_t)e*DD*DD + c0 + c;
  float acc[8] = {0,0,0,0,0,0,0,0};
#pragma unroll
  for (int i = 0; i < 32; ++i) {
    int d = kc*32 + i;
    float w = wp[(size_t)d*DD];
#pragma unroll
    for (int b = 0; b < 8; ++b) acc[b] += w * oS[b][d];
  }
#pragma unroll
  for (int b = 0; b < 8; ++b) op[kc][c][b] = acc[b];
  __syncthreads();
  int c2 = tid & 31, b2 = tid >> 5;
  float s = bp[e*DD + c0 + c2];
#pragma unroll
  for (int g = 0; g < 8; ++g) s += op[g][c2][b2];
  gateW[((size_t)(e*8 + b2))*DD + c0 + c2] = 1.f / (1.f + expf(-s));
}

// ================================================================ kernel 7: recombine (float4)
__global__ __launch_bounds__(256) void out_kernel(
    const float* __restrict__ x, const float* __restrict__ g1f, const float* __restrict__ g2f,
    const int* __restrict__ idx1a, const int* __restrict__ idx2a,
    const float* __restrict__ gateW, float* __restrict__ out)
{
  int idx = blockIdx.x*256 + threadIdx.x;   // float4 index
  int token = idx >> 6;
  int d4 = idx & 63;
  int b = token >> 11;
  float g1 = g1f[token], g2 = g2f[token];
  int e1 = idx1a[token], e2 = idx2a[token];
  float4 w1 = ((const float4*)(gateW + (size_t)(e1*BB+b)*DD))[d4];
  float4 w2 = ((const float4*)(gateW + (size_t)(e2*BB+b)*DD))[d4];
  float4 xv = ((const float4*)x)[idx];
  float4 o;
  o.x = xv.x*(g1*w1.x + g2*w2.x);
  o.y = xv.y*(g1*w1.y + g2*w2.y);
  o.z = xv.z*(g1*w1.z + g2*w2.z);
  o.w = xv.w*(g1*w1.w + g2*w2.w);
  ((float4*)out)[idx] = o;
}

// ================================================================ launcher
extern "C" void kernel_launch(void* const* d_in, const int* in_sizes, int n_in,
                              void* d_out, int out_size, void* d_ws, size_t ws_size,
                              hipStream_t stream)
{
  const float* x     = (const float*)d_in[0];
  const float* audio = (const float*)d_in[1];
  const float* wg    = (const float*)d_in[2];
  const float* Wq    = (const float*)d_in[3];
  const float* Wkv   = (const float*)d_in[4];
  const float* Wp    = (const float*)d_in[5];
  const float* bp    = (const float*)d_in[6];
  float* out = (float*)d_out;

  // workspace (~3.9 MB), no memsets needed
  float* raw_part = (float*)d_ws;                      // 256*16
  float* cnt_part = raw_part + 256*16;                 // 256*16
  int*   idx1a   = (int*)(cnt_part + 256*16);          // BN
  int*   idx2a   = idx1a + BN;                         // BN
  float* g1a     = (float*)(idx2a + BN);               // BN (scan truncates in place)
  float* g2a     = g1a + BN;                           // BN
  int*   slot_token = (int*)(g2a + BN);                // EB*CAP
  float* rws     = (float*)(slot_token + EB*CAPC);     // EB*2048
  float* lslot   = rws + (size_t)EB*2048;              // EB*CAP*8
  float* xattn   = lslot + (size_t)EB*CAPC*8;          // EB*2048
  float* o_ws    = xattn + (size_t)EB*2048;            // EB*256
  float* gateW   = o_ws + (size_t)EB*DD;               // EB*256

  fused_gq_kernel<<<384, 256, 0, stream>>>(x, wg, audio, Wq, Wkv,
                                           idx1a, idx2a, g1a, g2a,
                                           raw_part, cnt_part, rws);
  scan_kernel<<<BB, 256, 0, stream>>>(idx1a, idx2a, g1a, g2a, slot_token,
                                      raw_part, cnt_part, out + (size_t)out_size - 1);
  lslotB_kernel<<<EB*4, 256, 0, stream>>>(x, rws, slot_token, lslot);
  xattn_kernel<<<EB*4, 256, 0, stream>>>(x, lslot, slot_token, xattn);
  o_kernel<<<EB, 256, 0, stream>>>(xattn, Wkv, o_ws);
  gate_kernel<<<EB, 256, 0, stream>>>(o_ws, Wp, bp, gateW);
  out_kernel<<<(BN*DD/4)/256, 256, 0, stream>>>(x, g1a, g2a, idx1a, idx2a, gateW, out);
}